// Round 4
// baseline (503.981 us; speedup 1.0000x reference)
//
#include <hip/hip_runtime.h>
#include <math.h>

// CrossViewSwapAttention forward. Round 4: unified templated MFMA GEMM with
// LDS-repacked vectorized epilogue; all intermediates bf16.
// B=2 N=6 H=W=64 FH=32 FW=88 DIM=128 HEADS=4 DH=32 QW=8x8 KW=4x11

typedef __attribute__((ext_vector_type(8))) short short8;
typedef __attribute__((ext_vector_type(4))) float f32x4;

__device__ __forceinline__ unsigned short f2bf(float f){
  union { float f; unsigned u; } v; v.f = f;
  unsigned r = v.u + 0x7FFF + ((v.u >> 16) & 1);   // RNE
  return (unsigned short)(r >> 16);
}
__device__ __forceinline__ float bf2f(unsigned short h){
  union { unsigned u; float f; } v; v.u = ((unsigned)h) << 16; return v.f;
}
__device__ __forceinline__ void store_bf16x8(unsigned short* p, const float* v){
  union { short8 s8; unsigned short u[8]; } u;
  #pragma unroll
  for (int i=0;i<8;i++) u.u[i] = f2bf(v[i]);
  *(short8*)p = u.s8;
}

__device__ __forceinline__ size_t remap_kv(int tok, int mode){
  // tok = bn*2816 + i*88 + j  ->  KP/VP row ((b*64+l)*264 + t)
  int bn = tok / 2816; int p = tok - bn*2816;
  int b = bn / 6, n = bn - b*6;
  int i = p / 88, j = p - i*88;
  int l, t;
  if (mode == 1){            // stage 1: _win(k, 4, 11)
    int jw = j / 11;
    l = (i >> 2)*8 + jw;
    t = n*44 + (i & 3)*11 + (j - jw*11);
  } else {                   // stage 2: _gridwin(k, 4, 11)
    l = (i & 7)*8 + (j & 7);
    t = n*44 + (i >> 3)*11 + (j >> 3);
  }
  return (size_t)((b*64 + l)*264 + t);
}

// c_embed[bn][o] = sum_c W_cam[o][c] * E_inv[bn][c][3]
__global__ __launch_bounds__(128) void k_cembed(const float* __restrict__ Einv,
                                                const float* __restrict__ Wcam,
                                                float* __restrict__ CE){
  int bn = blockIdx.x, o = threadIdx.x;
  const float* E = Einv + bn*16;
  const float* W = Wcam + o*4;
  CE[bn*128 + o] = W[0]*E[3] + W[1]*E[7] + W[2]*E[11] + W[3]*E[15];
}

// one-time weight prep: fp32 [k][n] -> bf16 [n][k] (straight copy for conv Ws).
__global__ __launch_bounds__(256) void k_wprep(const float* __restrict__ qkv,
    const float* __restrict__ wp, const float* __restrict__ wma,
    const float* __restrict__ wmb, const float* __restrict__ wfl,
    const float* __restrict__ wfp, unsigned short* __restrict__ Wt){
  const int sel[14]  = {0,0,0,0,0,0,1,1,2,2,3,3,4,5};
  const int soff[14] = {0,16384,32768,49152,65536,81920,0,16384,0,32768,0,32768,0,0};
  const int doff[14] = {0,16384,32768,49152,65536,81920,98304,114688,131072,163840,196608,229376,262144,278528};
  const int Ks[14]   = {128,128,128,128,128,128,128,128,128,128,256,256,128,128};
  const int Ns[14]   = {128,128,128,128,128,128,128,128,256,256,128,128,128,128};
  const int trs[14]  = {1,1,1,1,1,1,1,1,1,1,1,1,0,0};
  int sg = blockIdx.x >> 2, q = blockIdx.x & 3;
  const float* srcs[6] = {qkv, wp, wma, wmb, wfl, wfp};
  const float* src = srcs[sel[sg]] + soff[sg];
  unsigned short* dst = Wt + doff[sg];
  int K = Ks[sg], N = Ns[sg];
  int quarter = (K*N) >> 2;
  for (int idx = q*quarter + threadIdx.x; idx < (q+1)*quarter; idx += 256){
    int n = idx / K, k = idx - n*K;
    float v = trs[sg] ? src[k*N + n] : src[idx];
    dst[idx] = f2bf(v);
  }
}

// img_embed (normalized over channel) -> K1h bf16 (bn,p,c)
__global__ __launch_bounds__(128) void k_geom(const float* __restrict__ Iinv,
                                              const float* __restrict__ Einv,
                                              const float* __restrict__ Wimg,
                                              const float* __restrict__ CE,
                                              unsigned short* __restrict__ K1h){
  int tile = blockIdx.x;               // bn*352 + tp  (8 pixels per block)
  int bn = tile / 352; int p0 = (tile - bn*352)*8;
  int xid = threadIdx.x >> 4, part = threadIdx.x & 15;
  int p = p0 + xid;
  int i = p / 88, j = p - i*88;
  float xs = (float)j * (480.0f/87.0f);
  float ys = (float)i * (224.0f/31.0f);
  const float* I = Iinv + bn*9;
  const float* E = Einv + bn*16;
  float c0 = I[0]*xs + I[1]*ys + I[2];
  float c1 = I[3]*xs + I[4]*ys + I[5];
  float c2 = I[6]*xs + I[7]*ys + I[8];
  float d0 = E[0]*c0 + E[1]*c1 + E[2]*c2 + E[3];
  float d1 = E[4]*c0 + E[5]*c1 + E[6]*c2 + E[7];
  float d2 = E[8]*c0 + E[9]*c1 + E[10]*c2 + E[11];
  float d3 = E[12]*c0 + E[13]*c1 + E[14]*c2 + E[15];
  float v[8]; float sq = 0.f;
  #pragma unroll
  for (int k=0;k<8;k++){
    int o = part*8 + k;
    const float* W = Wimg + o*4;
    float de = W[0]*d0 + W[1]*d1 + W[2]*d2 + W[3]*d3;
    float vv = de - CE[bn*128 + o];
    v[k] = vv; sq = fmaf(vv, vv, sq);
  }
  #pragma unroll
  for (int off=8; off>0; off>>=1) sq += __shfl_xor(sq, off, 16);
  float rn = 1.0f / fmaxf(sqrtf(sq), 1e-12f);
  float o8[8];
  #pragma unroll
  for (int k=0;k<8;k++) o8[k] = v[k]*rn;
  store_bf16x8(K1h + (size_t)(bn*2816 + p)*128 + part*8, o8);
}

// query = normalize(w_embed - c_embed) + x, stage-1 q LayerNorm folded in,
// emitted bf16 in stage-1 window-token order.
__global__ __launch_bounds__(128) void k_bevq2(const float* __restrict__ gridp,
    const float* __restrict__ Wbev, const float* __restrict__ bbev,
    const float* __restrict__ CE, const float* __restrict__ x,
    const float* __restrict__ lg, const float* __restrict__ lb,
    unsigned short* __restrict__ Qh){
  int tile = blockIdx.x;               // bn*512 + tp (8 pixels per block)
  int bn = tile >> 9; int pp0 = (tile & 511) << 3;
  int b = bn / 6, n = bn - b*6;
  int xid = threadIdx.x >> 4, part = threadIdx.x & 15;
  int pix = pp0 + xid;
  int h = pix >> 6, w = pix & 63;
  float g0 = gridp[pix], g1 = gridp[4096 + pix];
  float v[8]; float sq = 0.f;
  #pragma unroll
  for (int k=0;k<8;k++){
    int o = part*8 + k;
    float we = Wbev[o*2]*g0 + Wbev[o*2+1]*g1 + bbev[o];
    float vv = we - CE[bn*128 + o];
    v[k] = vv; sq = fmaf(vv, vv, sq);
  }
  #pragma unroll
  for (int off=8; off>0; off>>=1) sq += __shfl_xor(sq, off, 16);
  float rn = 1.0f / fmaxf(sqrtf(sq), 1e-12f);
  const float* xp = x + ((size_t)b*128)*4096 + pix;
  float q[8]; float s=0.f, s2=0.f;
  #pragma unroll
  for (int k=0;k<8;k++){
    int o = part*8 + k;
    q[k] = fmaf(v[k], rn, xp[(size_t)o*4096]);
    s += q[k]; s2 = fmaf(q[k], q[k], s2);
  }
  #pragma unroll
  for (int off=8; off>0; off>>=1){ s += __shfl_xor(s, off, 16); s2 += __shfl_xor(s2, off, 16); }
  float mean = s*(1.f/128.f);
  float rstd = rsqrtf(fmaxf(s2*(1.f/128.f) - mean*mean, 0.f) + 1e-5f);
  int l = (h>>3)*8 + (w>>3);
  int t = n*64 + (h&7)*8 + (w&7);
  size_t row = (size_t)((b*64 + l)*384 + t);
  float o8[8];
  #pragma unroll
  for (int k=0;k<8;k++){
    int c = part*8 + k;
    o8[k] = fmaf((q[k]-mean)*rstd, lg[c], lb[c]);
  }
  store_bf16x8(Qh + row*128 + part*8, o8);
}

// Unified MFMA GEMM. A: bf16 rows (pre=2, opt LN, KT=128 only for LN) or
// fp32 feat conv (pre=1, KT=128). W: bf16 [NT][KT]. Out: bf16, rows remapped
// by outmode, written via LDS repack as contiguous short8 segments.
template<int KT, int NT>
__global__ __launch_bounds__(256) void k_gemmT(
    const float* __restrict__ Xf, const unsigned short* __restrict__ Xh, int ldx,
    const float* __restrict__ lg, const float* __restrict__ lb,
    const unsigned short* __restrict__ Wt, const float* __restrict__ bias,
    unsigned short* __restrict__ OUTH, int ldout, float oscale,
    int M, int pre, int do_ln, int act, int outmode, int skip_mode,
    const float* __restrict__ skipf, const unsigned short* __restrict__ skiph,
    int ldskip){
  constexpr int KP_ = KT + 8;
  constexpr int NP_ = NT + 8;
  constexpr int TN = NT / 64;     // n-tiles per wave
  constexpr int KSEG = KT / 8;
  __shared__ unsigned short sW[NT*KP_];
  __shared__ unsigned short sA[64*KP_];
  __shared__ unsigned short sD[64*NP_];
  __shared__ float sg[128], sb[128], sbias[NT];
  const int tid = threadIdx.x;
  for (int i = tid; i < NT*KSEG; i += 256){
    int n = i / KSEG, k8 = (i - n*KSEG)*8;
    *(short8*)&sW[n*KP_ + k8] = *(const short8*)(Wt + (size_t)n*KT + k8);
  }
  if (tid < 128 && (do_ln || pre == 1)){ sg[tid]=lg[tid]; sb[tid]=lb[tid]; }
  for (int i = tid; i < NT; i += 256) sbias[i] = bias ? bias[i] : 0.f;
  const int lane = tid & 63, wv = tid >> 6;
  const int lane15 = lane & 15, quad = lane >> 4;
  const int n0 = wv * (NT/4);
  const int chunks = M >> 6;
  const float RSQ = rsqrtf(1.0f + 1e-5f);
  for (int ch = blockIdx.x; ch < chunks; ch += gridDim.x){
    const int base = ch << 6;
    __syncthreads();
    if (pre == 2){
      const int r = tid >> 2, part = tid & 3;
      const unsigned short* src = Xh + (size_t)(base+r)*ldx + part*(KT/4);
      unsigned short* dst = sA + r*KP_ + part*(KT/4);
      if (!do_ln){
        #pragma unroll
        for (int k=0;k<KT/4;k+=8) *(short8*)(dst+k) = *(const short8*)(src+k);
      } else {  // KT==128
        float v[32];
        #pragma unroll
        for (int k=0;k<32;k+=8){
          union { short8 s; unsigned short u[8]; } t;
          t.s = *(const short8*)(src+k);
          #pragma unroll
          for (int i2=0;i2<8;i2++) v[k+i2] = bf2f(t.u[i2]);
        }
        float s=0.f, s2=0.f;
        #pragma unroll
        for (int k=0;k<32;k++){ s += v[k]; s2 = fmaf(v[k],v[k],s2); }
        s  += __shfl_xor(s, 2, 4);  s  += __shfl_xor(s, 1, 4);
        s2 += __shfl_xor(s2, 2, 4); s2 += __shfl_xor(s2, 1, 4);
        float mean = s * (1.f/128.f);
        float rstd = rsqrtf(fmaxf(s2*(1.f/128.f) - mean*mean, 0.f) + 1e-5f);
        #pragma unroll
        for (int k=0;k<32;k++){
          int c = part*32 + k;
          v[k] = fmaf((v[k]-mean)*rstd, sg[c], sb[c]);
        }
        store_bf16x8(dst, v); store_bf16x8(dst+8, v+8);
        store_bf16x8(dst+16, v+16); store_bf16x8(dst+24, v+24);
      }
    } else {  // pre == 1: conv A from feat (bn,c,p), BN eval + relu; KT==128
      int prow = tid & 63, cseg = tid >> 6;
      int bn = base / 2816;
      int p = base - bn*2816 + prow;
      const float* fb = Xf + ((size_t)bn*128 + cseg*32)*2816 + p;
      #pragma unroll
      for (int i=0;i<32;i+=2){
        int c = cseg*32 + i;
        float t0 = fb[(size_t)i*2816] * RSQ;
        float t1 = fb[(size_t)(i+1)*2816] * RSQ;
        float y0 = fmaxf(fmaf(t0, sg[c],   sb[c]),   0.f);
        float y1 = fmaxf(fmaf(t1, sg[c+1], sb[c+1]), 0.f);
        unsigned u = (unsigned)f2bf(y0) | ((unsigned)f2bf(y1) << 16);
        *(unsigned*)&sA[prow*KP_ + c] = u;
      }
    }
    __syncthreads();
    f32x4 acc[4][TN];
    #pragma unroll
    for (int mt=0; mt<4; mt++)
      #pragma unroll
      for (int nt=0; nt<TN; nt++) acc[mt][nt] = (f32x4)0.f;
    const unsigned short* aptr = sA + lane15*KP_ + quad*8;
    const unsigned short* bptr = sW + (size_t)(n0 + lane15)*KP_ + quad*8;
    #pragma unroll
    for (int kk=0; kk<KT/32; kk++){
      short8 af[4], bf[TN];
      #pragma unroll
      for (int mt=0; mt<4; mt++) af[mt] = *(const short8*)(aptr + mt*16*KP_ + kk*32);
      #pragma unroll
      for (int nt=0; nt<TN; nt++) bf[nt] = *(const short8*)(bptr + nt*16*KP_ + kk*32);
      #pragma unroll
      for (int mt=0; mt<4; mt++)
        #pragma unroll
        for (int nt=0; nt<TN; nt++)
          acc[mt][nt] = __builtin_amdgcn_mfma_f32_16x16x32_bf16(af[mt], bf[nt], acc[mt][nt], 0,0,0);
    }
    #pragma unroll
    for (int mt=0; mt<4; mt++){
      #pragma unroll
      for (int nt=0; nt<TN; nt++){
        int col = n0 + nt*16 + lane15;
        float bsv = sbias[col];
        #pragma unroll
        for (int r4=0; r4<4; r4++){
          int row = mt*16 + quad*4 + r4;
          int rrow = base + row;
          float v = acc[mt][nt][r4] + bsv;
          if (act) v = 0.5f*v*(1.f + erff(v*0.70710678118654752f));
          if (skip_mode == 1){
            int bb = rrow >> 12, l = (rrow >> 6) & 63, pp = rrow & 63;
            int pix = (((l>>3)*8 + (pp>>3)) << 6) + (l&7)*8 + (pp&7);
            v += skipf[(size_t)bb*524288 + (size_t)col*4096 + pix];
          } else if (skip_mode == 2){
            v += bf2f(skiph[(size_t)rrow*ldskip + col]);
          }
          v *= oscale;
          sD[row*NP_ + col] = f2bf(v);
        }
      }
    }
    __syncthreads();
    constexpr int RSEG = NT/8;
    for (int i = tid; i < 64*RSEG; i += 256){
      int row = i / RSEG, seg = i - row*RSEG;
      int rrow = base + row;
      size_t orow = outmode ? remap_kv(rrow, outmode) : (size_t)rrow;
      *(short8*)(OUTH + orow*(size_t)ldout + seg*8) = *(const short8*)&sD[row*NP_ + seg*8];
    }
  }
}

// MFMA attention (unchanged from R3): one block per (b,l,head), 4 waves.
__global__ __launch_bounds__(256) void k_attn2(const unsigned short* __restrict__ QPh,
    const unsigned short* __restrict__ KPh, const unsigned short* __restrict__ VPh,
    unsigned short* __restrict__ AOh, int nrep, int nQ){
  __shared__ unsigned short Ksh[288*40];   // [key][32d + pad]
  __shared__ unsigned short Vt[32*296];    // [d][288key + pad]
  __shared__ unsigned short Psh[4*16*40];  // per-wave P tile
  __shared__ float rs[4*16];
  int hd = blockIdx.x & 3; int bl = blockIdx.x >> 2;
  size_t kvbase = (size_t)bl*264;
  int tid = threadIdx.x;
  for (int idx = tid; idx < 1056; idx += 256){
    int row = idx >> 2, seg = idx & 3;
    *(short8*)&Ksh[row*40 + seg*8] =
      *(const short8*)(KPh + (kvbase+row)*128 + hd*32 + seg*8);
  }
  for (int idx = tid; idx < 96; idx += 256){
    int row = 264 + (idx>>2), seg = idx & 3;
    short8 z = {0,0,0,0,0,0,0,0};
    *(short8*)&Ksh[row*40 + seg*8] = z;
  }
  for (int idx = tid; idx < 4224; idx += 256){
    int kp = idx >> 5, d = idx & 31;
    unsigned v0 = VPh[(kvbase + 2*kp)*128 + hd*32 + d];
    unsigned v1 = VPh[(kvbase + 2*kp + 1)*128 + hd*32 + d];
    *(unsigned*)&Vt[d*296 + 2*kp] = v0 | (v1 << 16);
  }
  for (int idx = tid; idx < 384; idx += 256){
    int d = idx / 12, kp = 132 + idx % 12;
    *(unsigned*)&Vt[d*296 + 2*kp] = 0u;
  }
  __syncthreads();
  const int wv = tid >> 6, lane = tid & 63;
  const int lane15 = lane & 15, quad = lane >> 4;
  unsigned short* Pw = Psh + wv*640;
  float* rsw = rs + wv*16;
  short8 vfrag[9][2];
  #pragma unroll
  for (int kc=0; kc<9; kc++){
    vfrag[kc][0] = *(const short8*)&Vt[(lane15)*296      + kc*32 + quad*8];
    vfrag[kc][1] = *(const short8*)&Vt[(16+lane15)*296   + kc*32 + quad*8];
  }
  f32x4 macc0 = (f32x4)0.f, macc1 = (f32x4)0.f;
  for (int cam = 0; cam < nrep; cam++){
    int qrow = bl*nQ + (cam*4 + wv)*16 + lane15;
    short8 qf = *(const short8*)(QPh + (size_t)qrow*128 + hd*32 + quad*8);
    f32x4 oa0 = (f32x4)0.f, oa1 = (f32x4)0.f;
    float rsum = 0.f;
    #pragma unroll
    for (int kc=0; kc<9; kc++){
      #pragma unroll
      for (int sub=0; sub<2; sub++){
        int kt = kc*2 + sub;
        short8 kf = *(const short8*)&Ksh[(kt*16 + lane15)*40 + quad*8];
        f32x4 st = __builtin_amdgcn_mfma_f32_16x16x32_bf16(kf, qf, (f32x4)0.f, 0,0,0);
        int kbase = kt*16 + quad*4;
        float e0 = (kbase+0 < 264) ? __expf(st[0]) : 0.f;
        float e1 = (kbase+1 < 264) ? __expf(st[1]) : 0.f;
        float e2 = (kbase+2 < 264) ? __expf(st[2]) : 0.f;
        float e3 = (kbase+3 < 264) ? __expf(st[3]) : 0.f;
        rsum += (e0+e1)+(e2+e3);
        uint2 pk;
        pk.x = (unsigned)f2bf(e0) | ((unsigned)f2bf(e1) << 16);
        pk.y = (unsigned)f2bf(e2) | ((unsigned)f2bf(e3) << 16);
        *(uint2*)&Pw[lane15*40 + sub*16 + quad*4] = pk;
      }
      short8 pf = *(const short8*)&Pw[lane15*40 + quad*8];
      oa0 = __builtin_amdgcn_mfma_f32_16x16x32_bf16(pf, vfrag[kc][0], oa0, 0,0,0);
      oa1 = __builtin_amdgcn_mfma_f32_16x16x32_bf16(pf, vfrag[kc][1], oa1, 0,0,0);
    }
    rsum += __shfl_xor(rsum, 16);
    rsum += __shfl_xor(rsum, 32);
    if (lane < 16) rsw[lane] = rsum;
    f32x4 rv = *(f32x4*)&rsw[quad*4];
    #pragma unroll
    for (int r=0;r<4;r++){
      float inv = 1.f / rv[r];
      macc0[r] = fmaf(oa0[r], inv, macc0[r]);
      macc1[r] = fmaf(oa1[r], inv, macc1[r]);
    }
  }
  float sc = (nrep == 6) ? (1.f/6.f) : 1.f;
  int pixb = wv*16 + quad*4;
  #pragma unroll
  for (int r=0;r<4;r++){
    size_t rowo = ((size_t)(bl*64 + pixb + r))*128 + hd*32;
    AOh[rowo + lane15]      = f2bf(macc0[r]*sc);
    AOh[rowo + 16 + lane15] = f2bf(macc1[r]*sc);
  }
}

// final LN (bf16 in) + transpose to (B,128,64,64) fp32
__global__ __launch_bounds__(128) void k_final(const unsigned short* __restrict__ Xh,
    const float* __restrict__ g, const float* __restrict__ be,
    float* __restrict__ out){
  __shared__ float st[1024];
  __shared__ float sm[8], sr[8];
  int r0 = blockIdx.x*8;
  int b = r0 >> 12, l = (r0 >> 6) & 63, p0 = r0 & 63;
  int h = (l >> 3)*8 + (p0 >> 3);
  int wbase = (l & 7)*8;
  {
    union { short8 s; unsigned short u[8]; } t;
    t.s = *(const short8*)(Xh + (size_t)r0*128 + threadIdx.x*8);
    #pragma unroll
    for (int i=0;i<8;i++) st[threadIdx.x*8 + i] = bf2f(t.u[i]);
  }
  __syncthreads();
  int xid = threadIdx.x >> 4, part = threadIdx.x & 15;
  float s=0.f, s2=0.f;
  #pragma unroll
  for (int k=0;k<8;k++){
    float v = st[xid*128 + part*8 + k];
    s += v; s2 = fmaf(v,v,s2);
  }
  #pragma unroll
  for (int off=8; off>0; off>>=1){ s += __shfl_xor(s, off, 16); s2 += __shfl_xor(s2, off, 16); }
  if (part == 0){
    float mean = s*(1.f/128.f);
    sm[xid] = mean;
    sr[xid] = rsqrtf(fmaxf(s2*(1.f/128.f) - mean*mean, 0.f) + 1e-5f);
  }
  __syncthreads();
  int o = threadIdx.x;
  float go = g[o], bo = be[o];
  size_t obase = ((size_t)(b*128 + o))*4096 + h*64 + wbase;
  float res[8];
  #pragma unroll
  for (int x=0;x<8;x++) res[x] = fmaf((st[x*128+o]-sm[x])*sr[x], go, bo);
  *(float4*)&out[obase]   = make_float4(res[0],res[1],res[2],res[3]);
  *(float4*)&out[obase+4] = make_float4(res[4],res[5],res[6],res[7]);
}

extern "C" void kernel_launch(void* const* d_in, const int* in_sizes, int n_in,
                              void* d_out, int out_size, void* d_ws, size_t ws_size,
                              hipStream_t stream) {
  (void)in_sizes; (void)n_in; (void)out_size; (void)ws_size;
  const float* x     = (const float*)d_in[1];
  const float* gridp = (const float*)d_in[2];
  const float* feat  = (const float*)d_in[3];
  const float* Iinv  = (const float*)d_in[4];
  const float* Einv  = (const float*)d_in[5];
  const float* gfl   = (const float*)d_in[6];
  const float* bfl   = (const float*)d_in[7];
  const float* Wfl   = (const float*)d_in[8];
  const float* gfp   = (const float*)d_in[9];
  const float* bfp   = (const float*)d_in[10];
  const float* Wfp   = (const float*)d_in[11];
  const float* Wbev  = (const float*)d_in[12];
  const float* bbev  = (const float*)d_in[13];
  const float* Wimg  = (const float*)d_in[14];
  const float* Wcam  = (const float*)d_in[15];
  const float* alng  = (const float*)d_in[16];
  const float* alnb  = (const float*)d_in[17];
  const float* aWqkv = (const float*)d_in[18];
  const float* abqkv = (const float*)d_in[19];
  const float* aWp   = (const float*)d_in[20];
  const float* abp   = (const float*)d_in[21];
  const float* png   = (const float*)d_in[22];
  const float* pnb   = (const float*)d_in[23];
  const float* Wma   = (const float*)d_in[24];
  const float* bma   = (const float*)d_in[25];
  const float* Wmb   = (const float*)d_in[26];
  const float* bmb   = (const float*)d_in[27];
  const float* postg = (const float*)d_in[28];
  const float* postb = (const float*)d_in[29];
  float* out = (float*)d_out;
  float* ws  = (float*)d_ws;
  const float QSC = 0.17677669529663687f;   // 32^-0.5 folded into q projections

  // ws layout: CE (fp32), Wt + all intermediates bf16 (~73 MB)
  float* CE = ws;                                        // 2048 f
  unsigned short* Wt  = (unsigned short*)(ws + 2048);    // 294912 ush
  unsigned short* K1h = (unsigned short*)(ws + 149504);  // 33792x128
  unsigned short* V1h = K1h + 4325376;
  unsigned short* KPh = V1h + 4325376;                   // 128win x 264 x 128
  unsigned short* VPh = KPh + 4325376;
  unsigned short* QPh = VPh + 4325376;                   // 49152x128
  unsigned short* Qbh = QPh + 6291456;                   // 49152x128
  unsigned short* AOh = Qbh + 6291456;                   // 8192x128
  unsigned short* CURh= AOh + 1048576;
  unsigned short* Hh  = CURh + 1048576;                  // 8192x256
  unsigned short* Q1h = Hh + 2097152;
  unsigned short* Q2h = Q1h + 1048576;

  unsigned short* WtQ1 = Wt;            unsigned short* WtK1 = Wt + 16384;
  unsigned short* WtV1 = Wt + 32768;    unsigned short* WtQ2 = Wt + 49152;
  unsigned short* WtK2 = Wt + 65536;    unsigned short* WtV2 = Wt + 81920;
  unsigned short* WtP1 = Wt + 98304;    unsigned short* WtP2 = Wt + 114688;
  unsigned short* WtMA1 = Wt + 131072;  unsigned short* WtMA2 = Wt + 163840;
  unsigned short* WtMB1 = Wt + 196608;  unsigned short* WtMB2 = Wt + 229376;
  unsigned short* WtFL = Wt + 262144;   unsigned short* WtFP = Wt + 278528;

  k_cembed<<<12, 128, 0, stream>>>(Einv, Wcam, CE);
  k_wprep<<<56, 256, 0, stream>>>(aWqkv, aWp, Wma, Wmb, Wfl, Wfp, Wt);
  k_geom<<<4224, 128, 0, stream>>>(Iinv, Einv, Wimg, CE, K1h);
  k_bevq2<<<6144, 128, 0, stream>>>(gridp, Wbev, bbev, CE, x, alng, alnb, Qbh);

  // conv: K1 = geom + Wfp@relu(bn(feat)); V1 = Wfl@relu(bn(feat))
  k_gemmT<128,128><<<528, 256, 0, stream>>>(feat, nullptr, 0, gfp, bfp, WtFP, nullptr,
      K1h, 128, 1.f, 33792, 1,0,0, 0, 2, nullptr, K1h, 128);
  k_gemmT<128,128><<<528, 256, 0, stream>>>(feat, nullptr, 0, gfl, bfl, WtFL, nullptr,
      V1h, 128, 1.f, 33792, 1,0,0, 0, 0, nullptr, nullptr, 0);

  // ---- stage 1 ----
  k_gemmT<128,128><<<768, 256, 0, stream>>>(nullptr, Qbh, 128, nullptr, nullptr, WtQ1, abqkv,
      QPh, 128, QSC, 49152, 2,0,0, 0, 0, nullptr, nullptr, 0);
  k_gemmT<128,128><<<528, 256, 0, stream>>>(nullptr, K1h, 128, alng+128, alnb+128, WtK1, abqkv+128,
      KPh, 128, 1.f, 33792, 2,1,0, 1, 0, nullptr, nullptr, 0);
  k_gemmT<128,128><<<528, 256, 0, stream>>>(nullptr, V1h, 128, alng+256, alnb+256, WtV1, abqkv+256,
      VPh, 128, 1.f, 33792, 2,1,0, 1, 0, nullptr, nullptr, 0);
  k_attn2<<<512, 256, 0, stream>>>(QPh, KPh, VPh, AOh, 6, 384);
  k_gemmT<128,128><<<128, 256, 0, stream>>>(nullptr, AOh, 128, nullptr, nullptr, WtP1, abp,
      CURh, 128, 1.f, 8192, 2,0,0, 0, 1, x, nullptr, 0);
  k_gemmT<128,256><<<128, 256, 0, stream>>>(nullptr, CURh, 128, png, pnb, WtMA1, bma,
      Hh, 256, 1.f, 8192, 2,1,1, 0, 0, nullptr, nullptr, 0);
  k_gemmT<256,128><<<128, 256, 0, stream>>>(nullptr, Hh, 256, nullptr, nullptr, WtMB1, bmb,
      Q1h, 128, 1.f, 8192, 2,0,0, 0, 2, nullptr, CURh, 128);

  // ---- stage 2 ----
  k_gemmT<128,128><<<128, 256, 0, stream>>>(nullptr, Q1h, 128, alng+384, alnb+384, WtQ2, abqkv+384,
      QPh, 128, QSC, 8192, 2,1,0, 0, 0, nullptr, nullptr, 0);
  k_gemmT<128,128><<<528, 256, 0, stream>>>(nullptr, K1h, 128, alng+512, alnb+512, WtK2, abqkv+512,
      KPh, 128, 1.f, 33792, 2,1,0, 2, 0, nullptr, nullptr, 0);
  k_gemmT<128,128><<<528, 256, 0, stream>>>(nullptr, V1h, 128, alng+640, alnb+640, WtV2, abqkv+640,
      VPh, 128, 1.f, 33792, 2,1,0, 2, 0, nullptr, nullptr, 0);
  k_attn2<<<512, 256, 0, stream>>>(QPh, KPh, VPh, AOh, 1, 64);
  k_gemmT<128,128><<<128, 256, 0, stream>>>(nullptr, AOh, 128, nullptr, nullptr, WtP2, abp+128,
      CURh, 128, 1.f, 8192, 2,0,0, 0, 2, nullptr, Q1h, 128);
  k_gemmT<128,256><<<128, 256, 0, stream>>>(nullptr, CURh, 128, png+128, pnb+128, WtMA2, bma+256,
      Hh, 256, 1.f, 8192, 2,1,1, 0, 0, nullptr, nullptr, 0);
  k_gemmT<256,128><<<128, 256, 0, stream>>>(nullptr, Hh, 256, nullptr, nullptr, WtMB2, bmb+128,
      Q2h, 128, 1.f, 8192, 2,0,0, 0, 2, nullptr, CURh, 128);

  k_final<<<1024, 128, 0, stream>>>(Q2h, postg, postb, out);
}

// Round 5
// 399.850 us; speedup vs baseline: 1.2604x; 1.2604x over previous
//
#include <hip/hip_runtime.h>
#include <math.h>

// CrossViewSwapAttention forward. Round 5: MLP gemms split back to 128-wide
// tiles (occupancy over merge), MT=32 chunks + LDS-aliased epilogue for all
// M=8192 gemms (3 WG/CU), inline polynomial gelu (no erff call).
// B=2 N=6 H=W=64 FH=32 FW=88 DIM=128 HEADS=4 DH=32 QW=8x8 KW=4x11

typedef __attribute__((ext_vector_type(8))) short short8;
typedef __attribute__((ext_vector_type(4))) float f32x4;

__device__ __forceinline__ unsigned short f2bf(float f){
  union { float f; unsigned u; } v; v.f = f;
  unsigned r = v.u + 0x7FFF + ((v.u >> 16) & 1);   // RNE
  return (unsigned short)(r >> 16);
}
__device__ __forceinline__ float bf2f(unsigned short h){
  union { unsigned u; float f; } v; v.u = ((unsigned)h) << 16; return v.f;
}
__device__ __forceinline__ void store_bf16x8(unsigned short* p, const float* v){
  union { short8 s8; unsigned short u[8]; } u;
  #pragma unroll
  for (int i=0;i<8;i++) u.u[i] = f2bf(v[i]);
  *(short8*)p = u.s8;
}

// gelu(x) = 0.5 x (1 + erf(x/sqrt2)); erf via A&S 7.1.26, |err| <= 1.5e-7.
__device__ __forceinline__ float gelu_erf(float x){
  float z = x * 0.70710678118654752f;
  float a = fabsf(z);
  float t = 1.0f / fmaf(0.3275911f, a, 1.0f);
  float p = t*(0.254829592f + t*(-0.284496736f + t*(1.421413741f +
            t*(-1.453152027f + t*1.061405429f))));
  float er = 1.0f - p*__expf(-a*a);
  er = copysignf(er, z);
  return 0.5f * x * (1.0f + er);
}

__device__ __forceinline__ size_t remap_kv(int tok, int mode){
  // tok = bn*2816 + i*88 + j  ->  KP/VP row ((b*64+l)*264 + t)
  int bn = tok / 2816; int p = tok - bn*2816;
  int b = bn / 6, n = bn - b*6;
  int i = p / 88, j = p - i*88;
  int l, t;
  if (mode == 1){            // stage 1: _win(k, 4, 11)
    int jw = j / 11;
    l = (i >> 2)*8 + jw;
    t = n*44 + (i & 3)*11 + (j - jw*11);
  } else {                   // stage 2: _gridwin(k, 4, 11)
    l = (i & 7)*8 + (j & 7);
    t = n*44 + (i >> 3)*11 + (j >> 3);
  }
  return (size_t)((b*64 + l)*264 + t);
}

// c_embed[bn][o] = sum_c W_cam[o][c] * E_inv[bn][c][3]
__global__ __launch_bounds__(128) void k_cembed(const float* __restrict__ Einv,
                                                const float* __restrict__ Wcam,
                                                float* __restrict__ CE){
  int bn = blockIdx.x, o = threadIdx.x;
  const float* E = Einv + bn*16;
  const float* W = Wcam + o*4;
  CE[bn*128 + o] = W[0]*E[3] + W[1]*E[7] + W[2]*E[11] + W[3]*E[15];
}

// one-time weight prep: fp32 [k][n] -> bf16 [n][k]; Wmb split into two
// [128][128] k-half blocks; conv Ws straight-copied.
__global__ __launch_bounds__(256) void k_wprep(const float* __restrict__ qkv,
    const float* __restrict__ wp, const float* __restrict__ wma,
    const float* __restrict__ wmb, const float* __restrict__ wfl,
    const float* __restrict__ wfp, unsigned short* __restrict__ Wt){
  const int sel[16]  = {0,0,0,0,0,0, 1,1, 2,2, 3,3,3,3, 4,5};
  const int soff[16] = {0,16384,32768,49152,65536,81920, 0,16384, 0,32768,
                        0,16384,32768,49152, 0,0};
  const int doff[16] = {0,16384,32768,49152,65536,81920, 98304,114688,
                        131072,163840, 196608,212992,229376,245760, 262144,278528};
  const int Ns[16]   = {128,128,128,128,128,128, 128,128, 256,256,
                        128,128,128,128, 128,128};
  const int trs[16]  = {1,1,1,1,1,1, 1,1, 1,1, 1,1,1,1, 0,0};
  int sg = blockIdx.x >> 2, q = blockIdx.x & 3;
  const float* srcs[6] = {qkv, wp, wma, wmb, wfl, wfp};
  const float* src = srcs[sel[sg]] + soff[sg];
  unsigned short* dst = Wt + doff[sg];
  int K = 128, N = Ns[sg];
  int quarter = (K*N) >> 2;
  for (int idx = q*quarter + threadIdx.x; idx < (q+1)*quarter; idx += 256){
    int n = idx / K, k = idx - n*K;
    float v = trs[sg] ? src[k*N + n] : src[idx];
    dst[idx] = f2bf(v);
  }
}

// img_embed (normalized over channel) -> K1h bf16 (bn,p,c)
__global__ __launch_bounds__(128) void k_geom(const float* __restrict__ Iinv,
                                              const float* __restrict__ Einv,
                                              const float* __restrict__ Wimg,
                                              const float* __restrict__ CE,
                                              unsigned short* __restrict__ K1h){
  int tile = blockIdx.x;               // bn*352 + tp  (8 pixels per block)
  int bn = tile / 352; int p0 = (tile - bn*352)*8;
  int xid = threadIdx.x >> 4, part = threadIdx.x & 15;
  int p = p0 + xid;
  int i = p / 88, j = p - i*88;
  float xs = (float)j * (480.0f/87.0f);
  float ys = (float)i * (224.0f/31.0f);
  const float* I = Iinv + bn*9;
  const float* E = Einv + bn*16;
  float c0 = I[0]*xs + I[1]*ys + I[2];
  float c1 = I[3]*xs + I[4]*ys + I[5];
  float c2 = I[6]*xs + I[7]*ys + I[8];
  float d0 = E[0]*c0 + E[1]*c1 + E[2]*c2 + E[3];
  float d1 = E[4]*c0 + E[5]*c1 + E[6]*c2 + E[7];
  float d2 = E[8]*c0 + E[9]*c1 + E[10]*c2 + E[11];
  float d3 = E[12]*c0 + E[13]*c1 + E[14]*c2 + E[15];
  float v[8]; float sq = 0.f;
  #pragma unroll
  for (int k=0;k<8;k++){
    int o = part*8 + k;
    const float* W = Wimg + o*4;
    float de = W[0]*d0 + W[1]*d1 + W[2]*d2 + W[3]*d3;
    float vv = de - CE[bn*128 + o];
    v[k] = vv; sq = fmaf(vv, vv, sq);
  }
  #pragma unroll
  for (int off=8; off>0; off>>=1) sq += __shfl_xor(sq, off, 16);
  float rn = 1.0f / fmaxf(sqrtf(sq), 1e-12f);
  float o8[8];
  #pragma unroll
  for (int k=0;k<8;k++) o8[k] = v[k]*rn;
  store_bf16x8(K1h + (size_t)(bn*2816 + p)*128 + part*8, o8);
}

// query = normalize(w_embed - c_embed) + x, stage-1 q LayerNorm folded in,
// emitted bf16 in stage-1 window-token order.
__global__ __launch_bounds__(128) void k_bevq2(const float* __restrict__ gridp,
    const float* __restrict__ Wbev, const float* __restrict__ bbev,
    const float* __restrict__ CE, const float* __restrict__ x,
    const float* __restrict__ lg, const float* __restrict__ lb,
    unsigned short* __restrict__ Qh){
  int tile = blockIdx.x;               // bn*512 + tp (8 pixels per block)
  int bn = tile >> 9; int pp0 = (tile & 511) << 3;
  int b = bn / 6, n = bn - b*6;
  int xid = threadIdx.x >> 4, part = threadIdx.x & 15;
  int pix = pp0 + xid;
  int h = pix >> 6, w = pix & 63;
  float g0 = gridp[pix], g1 = gridp[4096 + pix];
  float v[8]; float sq = 0.f;
  #pragma unroll
  for (int k=0;k<8;k++){
    int o = part*8 + k;
    float we = Wbev[o*2]*g0 + Wbev[o*2+1]*g1 + bbev[o];
    float vv = we - CE[bn*128 + o];
    v[k] = vv; sq = fmaf(vv, vv, sq);
  }
  #pragma unroll
  for (int off=8; off>0; off>>=1) sq += __shfl_xor(sq, off, 16);
  float rn = 1.0f / fmaxf(sqrtf(sq), 1e-12f);
  const float* xp = x + ((size_t)b*128)*4096 + pix;
  float q[8]; float s=0.f, s2=0.f;
  #pragma unroll
  for (int k=0;k<8;k++){
    int o = part*8 + k;
    q[k] = fmaf(v[k], rn, xp[(size_t)o*4096]);
    s += q[k]; s2 = fmaf(q[k], q[k], s2);
  }
  #pragma unroll
  for (int off=8; off>0; off>>=1){ s += __shfl_xor(s, off, 16); s2 += __shfl_xor(s2, off, 16); }
  float mean = s*(1.f/128.f);
  float rstd = rsqrtf(fmaxf(s2*(1.f/128.f) - mean*mean, 0.f) + 1e-5f);
  int l = (h>>3)*8 + (w>>3);
  int t = n*64 + (h&7)*8 + (w&7);
  size_t row = (size_t)((b*64 + l)*384 + t);
  float o8[8];
  #pragma unroll
  for (int k=0;k<8;k++){
    int c = part*8 + k;
    o8[k] = fmaf((q[k]-mean)*rstd, lg[c], lb[c]);
  }
  store_bf16x8(Qh + row*128 + part*8, o8);
}

// Unified MFMA GEMM, KT=NT=128 tiles, MT rows per chunk (32 or 64).
// pre: 1 = conv from fp32 feat (BN+relu, MT=64 only), 2 = bf16 rows (opt LN).
// Epilogue result repacked through sA (aliased) and stored as short8 rows.
template<int MT>
__global__ __launch_bounds__(256) void k_gemmT(
    const float* __restrict__ Xf, const unsigned short* __restrict__ Xh, int ldx,
    const float* __restrict__ lg, const float* __restrict__ lb,
    const unsigned short* __restrict__ Wt, const float* __restrict__ bias,
    unsigned short* __restrict__ OUTH, int ldout, float oscale,
    int M, int pre, int do_ln, int act, int outmode, int skip_mode,
    const float* __restrict__ skipf, const unsigned short* __restrict__ skiph,
    int ldskip){
  constexpr int KP_ = 136;          // 128 + 8 pad (shorts)
  constexpr int MTILES = MT / 16;
  constexpr int TPR = 256 / MT;     // threads per row (4 or 8)
  constexpr int KPT = 128 / TPR;    // k elems per thread (32 or 16)
  __shared__ unsigned short sW[128*KP_];
  __shared__ unsigned short sA[MT*KP_];   // A tile; reused as D tile
  __shared__ float sg[128], sb[128], sbias[128];
  const int tid = threadIdx.x;
  for (int i = tid; i < 2048; i += 256){
    int n = i >> 4, k8 = (i & 15) << 3;
    *(short8*)&sW[n*KP_ + k8] = *(const short8*)(Wt + (size_t)n*128 + k8);
  }
  if (tid < 128){
    if (do_ln || pre == 1){ sg[tid]=lg[tid]; sb[tid]=lb[tid]; }
    sbias[tid] = bias ? bias[tid] : 0.f;
  }
  const int lane = tid & 63, wv = tid >> 6;
  const int lane15 = lane & 15, quad = lane >> 4;
  const int n0 = wv * 32;
  const int chunks = M / MT;
  const float RSQ = rsqrtf(1.0f + 1e-5f);
  for (int ch = blockIdx.x; ch < chunks; ch += gridDim.x){
    const int base = ch * MT;
    __syncthreads();                       // prior store-phase done with sA
    if (pre == 2){
      const int r = tid / TPR, part = tid % TPR;
      const unsigned short* src = Xh + (size_t)(base+r)*ldx + part*KPT;
      unsigned short* dst = sA + r*KP_ + part*KPT;
      if (!do_ln){
        #pragma unroll
        for (int k=0;k<KPT;k+=8) *(short8*)(dst+k) = *(const short8*)(src+k);
      } else {
        float v[KPT];
        #pragma unroll
        for (int k=0;k<KPT;k+=8){
          union { short8 s; unsigned short u[8]; } t;
          t.s = *(const short8*)(src+k);
          #pragma unroll
          for (int i2=0;i2<8;i2++) v[k+i2] = bf2f(t.u[i2]);
        }
        float s=0.f, s2=0.f;
        #pragma unroll
        for (int k=0;k<KPT;k++){ s += v[k]; s2 = fmaf(v[k],v[k],s2); }
        #pragma unroll
        for (int off=TPR/2; off>0; off>>=1){
          s += __shfl_xor(s, off, TPR); s2 += __shfl_xor(s2, off, TPR);
        }
        float mean = s * (1.f/128.f);
        float rstd = rsqrtf(fmaxf(s2*(1.f/128.f) - mean*mean, 0.f) + 1e-5f);
        #pragma unroll
        for (int k=0;k<KPT;k++){
          int c = part*KPT + k;
          v[k] = fmaf((v[k]-mean)*rstd, sg[c], sb[c]);
        }
        #pragma unroll
        for (int k=0;k<KPT;k+=8) store_bf16x8(dst+k, v+k);
      }
    } else {  // pre == 1: conv from feat (bn,c,p), BN eval + relu; MT=64
      int prow = tid & 63, cseg = tid >> 6;
      int bn = base / 2816;
      int p = base - bn*2816 + prow;
      const float* fb = Xf + ((size_t)bn*128 + cseg*32)*2816 + p;
      #pragma unroll
      for (int i=0;i<32;i+=2){
        int c = cseg*32 + i;
        float t0 = fb[(size_t)i*2816] * RSQ;
        float t1 = fb[(size_t)(i+1)*2816] * RSQ;
        float y0 = fmaxf(fmaf(t0, sg[c],   sb[c]),   0.f);
        float y1 = fmaxf(fmaf(t1, sg[c+1], sb[c+1]), 0.f);
        unsigned u = (unsigned)f2bf(y0) | ((unsigned)f2bf(y1) << 16);
        *(unsigned*)&sA[prow*KP_ + c] = u;
      }
    }
    __syncthreads();
    f32x4 acc[MTILES][2];
    #pragma unroll
    for (int mt=0; mt<MTILES; mt++){ acc[mt][0]=(f32x4)0.f; acc[mt][1]=(f32x4)0.f; }
    const unsigned short* aptr = sA + lane15*KP_ + quad*8;
    const unsigned short* bptr = sW + (size_t)(n0 + lane15)*KP_ + quad*8;
    #pragma unroll
    for (int kk=0; kk<4; kk++){
      short8 af[MTILES], bf2[2];
      #pragma unroll
      for (int mt=0; mt<MTILES; mt++) af[mt] = *(const short8*)(aptr + mt*16*KP_ + kk*32);
      bf2[0] = *(const short8*)(bptr + kk*32);
      bf2[1] = *(const short8*)(bptr + 16*KP_ + kk*32);
      #pragma unroll
      for (int mt=0; mt<MTILES; mt++){
        acc[mt][0] = __builtin_amdgcn_mfma_f32_16x16x32_bf16(af[mt], bf2[0], acc[mt][0], 0,0,0);
        acc[mt][1] = __builtin_amdgcn_mfma_f32_16x16x32_bf16(af[mt], bf2[1], acc[mt][1], 0,0,0);
      }
    }
    __syncthreads();                       // all waves done reading sA
    #pragma unroll
    for (int mt=0; mt<MTILES; mt++){
      #pragma unroll
      for (int nt=0; nt<2; nt++){
        int col = n0 + nt*16 + lane15;
        float bsv = sbias[col];
        #pragma unroll
        for (int r4=0; r4<4; r4++){
          int row = mt*16 + quad*4 + r4;
          int rrow = base + row;
          float v = acc[mt][nt][r4] + bsv;
          if (act) v = gelu_erf(v);
          if (skip_mode == 1){
            int bb = rrow >> 12, l = (rrow >> 6) & 63, pp = rrow & 63;
            int pix = (((l>>3)*8 + (pp>>3)) << 6) + (l&7)*8 + (pp&7);
            v += skipf[(size_t)bb*524288 + (size_t)col*4096 + pix];
          } else if (skip_mode == 2){
            v += bf2f(skiph[(size_t)rrow*ldskip + col]);
          }
          v *= oscale;
          sA[row*KP_ + col] = f2bf(v);     // D tile aliases A tile
        }
      }
    }
    __syncthreads();
    for (int i = tid; i < MT*16; i += 256){
      int row = i >> 4, seg = i & 15;
      int rrow = base + row;
      size_t orow = outmode ? remap_kv(rrow, outmode) : (size_t)rrow;
      *(short8*)(OUTH + orow*(size_t)ldout + seg*8) = *(const short8*)&sA[row*KP_ + seg*8];
    }
  }
}

// MFMA attention: one block per (b,l,head), 4 waves.
__global__ __launch_bounds__(256) void k_attn2(const unsigned short* __restrict__ QPh,
    const unsigned short* __restrict__ KPh, const unsigned short* __restrict__ VPh,
    unsigned short* __restrict__ AOh, int nrep, int nQ){
  __shared__ unsigned short Ksh[288*40];   // [key][32d + pad]
  __shared__ unsigned short Vt[32*296];    // [d][288key + pad]
  __shared__ unsigned short Psh[4*16*40];  // per-wave P tile
  __shared__ float rs[4*16];
  int hd = blockIdx.x & 3; int bl = blockIdx.x >> 2;
  size_t kvbase = (size_t)bl*264;
  int tid = threadIdx.x;
  for (int idx = tid; idx < 1056; idx += 256){
    int row = idx >> 2, seg = idx & 3;
    *(short8*)&Ksh[row*40 + seg*8] =
      *(const short8*)(KPh + (kvbase+row)*128 + hd*32 + seg*8);
  }
  for (int idx = tid; idx < 96; idx += 256){
    int row = 264 + (idx>>2), seg = idx & 3;
    short8 z = {0,0,0,0,0,0,0,0};
    *(short8*)&Ksh[row*40 + seg*8] = z;
  }
  for (int idx = tid; idx < 4224; idx += 256){
    int kp = idx >> 5, d = idx & 31;
    unsigned v0 = VPh[(kvbase + 2*kp)*128 + hd*32 + d];
    unsigned v1 = VPh[(kvbase + 2*kp + 1)*128 + hd*32 + d];
    *(unsigned*)&Vt[d*296 + 2*kp] = v0 | (v1 << 16);
  }
  for (int idx = tid; idx < 384; idx += 256){
    int d = idx / 12, kp = 132 + idx % 12;
    *(unsigned*)&Vt[d*296 + 2*kp] = 0u;
  }
  __syncthreads();
  const int wv = tid >> 6, lane = tid & 63;
  const int lane15 = lane & 15, quad = lane >> 4;
  unsigned short* Pw = Psh + wv*640;
  float* rsw = rs + wv*16;
  short8 vfrag[9][2];
  #pragma unroll
  for (int kc=0; kc<9; kc++){
    vfrag[kc][0] = *(const short8*)&Vt[(lane15)*296      + kc*32 + quad*8];
    vfrag[kc][1] = *(const short8*)&Vt[(16+lane15)*296   + kc*32 + quad*8];
  }
  f32x4 macc0 = (f32x4)0.f, macc1 = (f32x4)0.f;
  for (int cam = 0; cam < nrep; cam++){
    int qrow = bl*nQ + (cam*4 + wv)*16 + lane15;
    short8 qf = *(const short8*)(QPh + (size_t)qrow*128 + hd*32 + quad*8);
    f32x4 oa0 = (f32x4)0.f, oa1 = (f32x4)0.f;
    float rsum = 0.f;
    #pragma unroll
    for (int kc=0; kc<9; kc++){
      #pragma unroll
      for (int sub=0; sub<2; sub++){
        int kt = kc*2 + sub;
        short8 kf = *(const short8*)&Ksh[(kt*16 + lane15)*40 + quad*8];
        f32x4 st = __builtin_amdgcn_mfma_f32_16x16x32_bf16(kf, qf, (f32x4)0.f, 0,0,0);
        int kbase = kt*16 + quad*4;
        float e0 = (kbase+0 < 264) ? __expf(st[0]) : 0.f;
        float e1 = (kbase+1 < 264) ? __expf(st[1]) : 0.f;
        float e2 = (kbase+2 < 264) ? __expf(st[2]) : 0.f;
        float e3 = (kbase+3 < 264) ? __expf(st[3]) : 0.f;
        rsum += (e0+e1)+(e2+e3);
        uint2 pk;
        pk.x = (unsigned)f2bf(e0) | ((unsigned)f2bf(e1) << 16);
        pk.y = (unsigned)f2bf(e2) | ((unsigned)f2bf(e3) << 16);
        *(uint2*)&Pw[lane15*40 + sub*16 + quad*4] = pk;
      }
      short8 pf = *(const short8*)&Pw[lane15*40 + quad*8];
      oa0 = __builtin_amdgcn_mfma_f32_16x16x32_bf16(pf, vfrag[kc][0], oa0, 0,0,0);
      oa1 = __builtin_amdgcn_mfma_f32_16x16x32_bf16(pf, vfrag[kc][1], oa1, 0,0,0);
    }
    rsum += __shfl_xor(rsum, 16);
    rsum += __shfl_xor(rsum, 32);
    if (lane < 16) rsw[lane] = rsum;
    f32x4 rv = *(f32x4*)&rsw[quad*4];
    #pragma unroll
    for (int r=0;r<4;r++){
      float inv = 1.f / rv[r];
      macc0[r] = fmaf(oa0[r], inv, macc0[r]);
      macc1[r] = fmaf(oa1[r], inv, macc1[r]);
    }
  }
  float sc = (nrep == 6) ? (1.f/6.f) : 1.f;
  int pixb = wv*16 + quad*4;
  #pragma unroll
  for (int r=0;r<4;r++){
    size_t rowo = ((size_t)(bl*64 + pixb + r))*128 + hd*32;
    AOh[rowo + lane15]      = f2bf(macc0[r]*sc);
    AOh[rowo + 16 + lane15] = f2bf(macc1[r]*sc);
  }
}

// final LN (bf16 in) + transpose to (B,128,64,64) fp32
__global__ __launch_bounds__(128) void k_final(const unsigned short* __restrict__ Xh,
    const float* __restrict__ g, const float* __restrict__ be,
    float* __restrict__ out){
  __shared__ float st[1024];
  __shared__ float sm[8], sr[8];
  int r0 = blockIdx.x*8;
  int b = r0 >> 12, l = (r0 >> 6) & 63, p0 = r0 & 63;
  int h = (l >> 3)*8 + (p0 >> 3);
  int wbase = (l & 7)*8;
  {
    union { short8 s; unsigned short u[8]; } t;
    t.s = *(const short8*)(Xh + (size_t)r0*128 + threadIdx.x*8);
    #pragma unroll
    for (int i=0;i<8;i++) st[threadIdx.x*8 + i] = bf2f(t.u[i]);
  }
  __syncthreads();
  int xid = threadIdx.x >> 4, part = threadIdx.x & 15;
  float s=0.f, s2=0.f;
  #pragma unroll
  for (int k=0;k<8;k++){
    float v = st[xid*128 + part*8 + k];
    s += v; s2 = fmaf(v,v,s2);
  }
  #pragma unroll
  for (int off=8; off>0; off>>=1){ s += __shfl_xor(s, off, 16); s2 += __shfl_xor(s2, off, 16); }
  if (part == 0){
    float mean = s*(1.f/128.f);
    sm[xid] = mean;
    sr[xid] = rsqrtf(fmaxf(s2*(1.f/128.f) - mean*mean, 0.f) + 1e-5f);
  }
  __syncthreads();
  int o = threadIdx.x;
  float go = g[o], bo = be[o];
  size_t obase = ((size_t)(b*128 + o))*4096 + h*64 + wbase;
  float res[8];
  #pragma unroll
  for (int x=0;x<8;x++) res[x] = fmaf((st[x*128+o]-sm[x])*sr[x], go, bo);
  *(float4*)&out[obase]   = make_float4(res[0],res[1],res[2],res[3]);
  *(float4*)&out[obase+4] = make_float4(res[4],res[5],res[6],res[7]);
}

extern "C" void kernel_launch(void* const* d_in, const int* in_sizes, int n_in,
                              void* d_out, int out_size, void* d_ws, size_t ws_size,
                              hipStream_t stream) {
  (void)in_sizes; (void)n_in; (void)out_size; (void)ws_size;
  const float* x     = (const float*)d_in[1];
  const float* gridp = (const float*)d_in[2];
  const float* feat  = (const float*)d_in[3];
  const float* Iinv  = (const float*)d_in[4];
  const float* Einv  = (const float*)d_in[5];
  const float* gfl   = (const float*)d_in[6];
  const float* bfl   = (const float*)d_in[7];
  const float* Wfl   = (const float*)d_in[8];
  const float* gfp   = (const float*)d_in[9];
  const float* bfp   = (const float*)d_in[10];
  const float* Wfp   = (const float*)d_in[11];
  const float* Wbev  = (const float*)d_in[12];
  const float* bbev  = (const float*)d_in[13];
  const float* Wimg  = (const float*)d_in[14];
  const float* Wcam  = (const float*)d_in[15];
  const float* alng  = (const float*)d_in[16];
  const float* alnb  = (const float*)d_in[17];
  const float* aWqkv = (const float*)d_in[18];
  const float* abqkv = (const float*)d_in[19];
  const float* aWp   = (const float*)d_in[20];
  const float* abp   = (const float*)d_in[21];
  const float* png   = (const float*)d_in[22];
  const float* pnb   = (const float*)d_in[23];
  const float* Wma   = (const float*)d_in[24];
  const float* bma   = (const float*)d_in[25];
  const float* Wmb   = (const float*)d_in[26];
  const float* bmb   = (const float*)d_in[27];
  const float* postg = (const float*)d_in[28];
  const float* postb = (const float*)d_in[29];
  float* out = (float*)d_out;
  float* ws  = (float*)d_ws;
  const float QSC = 0.17677669529663687f;   // 32^-0.5 folded into q projections

  float* CE = ws;                                        // 2048 f
  unsigned short* Wt  = (unsigned short*)(ws + 2048);    // 294912 ush
  unsigned short* K1h = (unsigned short*)(ws + 149504);  // 33792x128
  unsigned short* V1h = K1h + 4325376;
  unsigned short* KPh = V1h + 4325376;                   // 128win x 264 x 128
  unsigned short* VPh = KPh + 4325376;
  unsigned short* QPh = VPh + 4325376;                   // 49152x128
  unsigned short* Qbh = QPh + 6291456;                   // 49152x128
  unsigned short* AOh = Qbh + 6291456;                   // 8192x128
  unsigned short* CURh= AOh + 1048576;
  unsigned short* Hh  = CURh + 1048576;                  // 8192x256
  unsigned short* Q1h = Hh + 2097152;
  unsigned short* Q2h = Q1h + 1048576;

  unsigned short* WtQ1 = Wt;            unsigned short* WtK1 = Wt + 16384;
  unsigned short* WtV1 = Wt + 32768;    unsigned short* WtQ2 = Wt + 49152;
  unsigned short* WtK2 = Wt + 65536;    unsigned short* WtV2 = Wt + 81920;
  unsigned short* WtP1 = Wt + 98304;    unsigned short* WtP2 = Wt + 114688;
  unsigned short* WtMA1 = Wt + 131072;  unsigned short* WtMA2 = Wt + 163840;
  unsigned short* WtMB1 = Wt + 196608;  unsigned short* WtMB2 = Wt + 229376;
  unsigned short* WtFL = Wt + 262144;   unsigned short* WtFP = Wt + 278528;

  k_cembed<<<12, 128, 0, stream>>>(Einv, Wcam, CE);
  k_wprep<<<64, 256, 0, stream>>>(aWqkv, aWp, Wma, Wmb, Wfl, Wfp, Wt);
  k_geom<<<4224, 128, 0, stream>>>(Iinv, Einv, Wimg, CE, K1h);
  k_bevq2<<<6144, 128, 0, stream>>>(gridp, Wbev, bbev, CE, x, alng, alnb, Qbh);

  // conv: K1 = geom + Wfp@relu(bn(feat)); V1 = Wfl@relu(bn(feat))
  k_gemmT<64><<<528, 256, 0, stream>>>(feat, nullptr, 0, gfp, bfp, WtFP, nullptr,
      K1h, 128, 1.f, 33792, 1,0,0, 0, 2, nullptr, K1h, 128);
  k_gemmT<64><<<528, 256, 0, stream>>>(feat, nullptr, 0, gfl, bfl, WtFL, nullptr,
      V1h, 128, 1.f, 33792, 1,0,0, 0, 0, nullptr, nullptr, 0);

  // ---- stage 1 ----
  k_gemmT<64><<<768, 256, 0, stream>>>(nullptr, Qbh, 128, nullptr, nullptr, WtQ1, abqkv,
      QPh, 128, QSC, 49152, 2,0,0, 0, 0, nullptr, nullptr, 0);
  k_gemmT<64><<<528, 256, 0, stream>>>(nullptr, K1h, 128, alng+128, alnb+128, WtK1, abqkv+128,
      KPh, 128, 1.f, 33792, 2,1,0, 1, 0, nullptr, nullptr, 0);
  k_gemmT<64><<<528, 256, 0, stream>>>(nullptr, V1h, 128, alng+256, alnb+256, WtV1, abqkv+256,
      VPh, 128, 1.f, 33792, 2,1,0, 1, 0, nullptr, nullptr, 0);
  k_attn2<<<512, 256, 0, stream>>>(QPh, KPh, VPh, AOh, 6, 384);
  k_gemmT<32><<<256, 256, 0, stream>>>(nullptr, AOh, 128, nullptr, nullptr, WtP1, abp,
      CURh, 128, 1.f, 8192, 2,0,0, 0, 1, x, nullptr, 0);
  k_gemmT<32><<<256, 256, 0, stream>>>(nullptr, CURh, 128, png, pnb, WtMA1, bma,
      Hh, 256, 1.f, 8192, 2,1,1, 0, 0, nullptr, nullptr, 0);
  k_gemmT<32><<<256, 256, 0, stream>>>(nullptr, CURh, 128, png, pnb, WtMA1+16384, bma+128,
      Hh+128, 256, 1.f, 8192, 2,1,1, 0, 0, nullptr, nullptr, 0);
  k_gemmT<32><<<256, 256, 0, stream>>>(nullptr, Hh, 256, nullptr, nullptr, WtMB1, bmb,
      Q1h, 128, 1.f, 8192, 2,0,0, 0, 2, nullptr, CURh, 128);
  k_gemmT<32><<<256, 256, 0, stream>>>(nullptr, Hh+128, 256, nullptr, nullptr, WtMB1+16384, nullptr,
      Q1h, 128, 1.f, 8192, 2,0,0, 0, 2, nullptr, Q1h, 128);

  // ---- stage 2 ----
  k_gemmT<32><<<256, 256, 0, stream>>>(nullptr, Q1h, 128, alng+384, alnb+384, WtQ2, abqkv+384,
      QPh, 128, QSC, 8192, 2,1,0, 0, 0, nullptr, nullptr, 0);
  k_gemmT<64><<<528, 256, 0, stream>>>(nullptr, K1h, 128, alng+512, alnb+512, WtK2, abqkv+512,
      KPh, 128, 1.f, 33792, 2,1,0, 2, 0, nullptr, nullptr, 0);
  k_gemmT<64><<<528, 256, 0, stream>>>(nullptr, V1h, 128, alng+640, alnb+640, WtV2, abqkv+640,
      VPh, 128, 1.f, 33792, 2,1,0, 2, 0, nullptr, nullptr, 0);
  k_attn2<<<512, 256, 0, stream>>>(QPh, KPh, VPh, AOh, 1, 64);
  k_gemmT<32><<<256, 256, 0, stream>>>(nullptr, AOh, 128, nullptr, nullptr, WtP2, abp+128,
      CURh, 128, 1.f, 8192, 2,0,0, 0, 2, nullptr, Q1h, 128);
  k_gemmT<32><<<256, 256, 0, stream>>>(nullptr, CURh, 128, png+128, pnb+128, WtMA2, bma+256,
      Hh, 256, 1.f, 8192, 2,1,1, 0, 0, nullptr, nullptr, 0);
  k_gemmT<32><<<256, 256, 0, stream>>>(nullptr, CURh, 128, png+128, pnb+128, WtMA2+16384, bma+384,
      Hh+128, 256, 1.f, 8192, 2,1,1, 0, 0, nullptr, nullptr, 0);
  k_gemmT<32><<<256, 256, 0, stream>>>(nullptr, Hh, 256, nullptr, nullptr, WtMB2, bmb+128,
      Q2h, 128, 1.f, 8192, 2,0,0, 0, 2, nullptr, CURh, 128);
  k_gemmT<32><<<256, 256, 0, stream>>>(nullptr, Hh+128, 256, nullptr, nullptr, WtMB2+16384, nullptr,
      Q2h, 128, 1.f, 8192, 2,0,0, 0, 2, nullptr, Q2h, 128);

  k_final<<<1024, 128, 0, stream>>>(Q2h, postg, postb, out);
}

// Round 6
// 315.068 us; speedup vs baseline: 1.5996x; 1.2691x over previous
//
#include <hip/hip_runtime.h>
#include <math.h>

// CrossViewSwapAttention forward. Round 6: dispatch fusion 26 -> 15.
// prep(wprep+cembed+geom+bevq2) / conv K+V merged / KV-proj merged /
// MA halves merged / MB as single KT=256 kernel / vectorized attn V staging.
// B=2 N=6 H=W=64 FH=32 FW=88 DIM=128 HEADS=4 DH=32 QW=8x8 KW=4x11

typedef __attribute__((ext_vector_type(8))) short short8;
typedef __attribute__((ext_vector_type(4))) float f32x4;

__device__ __forceinline__ unsigned short f2bf(float f){
  union { float f; unsigned u; } v; v.f = f;
  unsigned r = v.u + 0x7FFF + ((v.u >> 16) & 1);   // RNE
  return (unsigned short)(r >> 16);
}
__device__ __forceinline__ float bf2f(unsigned short h){
  union { unsigned u; float f; } v; v.u = ((unsigned)h) << 16; return v.f;
}
__device__ __forceinline__ void store_bf16x8(unsigned short* p, const float* v){
  union { short8 s8; unsigned short u[8]; } u;
  #pragma unroll
  for (int i=0;i<8;i++) u.u[i] = f2bf(v[i]);
  *(short8*)p = u.s8;
}

// gelu(x) = 0.5 x (1 + erf(x/sqrt2)); erf via A&S 7.1.26, |err| <= 1.5e-7.
__device__ __forceinline__ float gelu_erf(float x){
  float z = x * 0.70710678118654752f;
  float a = fabsf(z);
  float t = 1.0f / fmaf(0.3275911f, a, 1.0f);
  float p = t*(0.254829592f + t*(-0.284496736f + t*(1.421413741f +
            t*(-1.453152027f + t*1.061405429f))));
  float er = 1.0f - p*__expf(-a*a);
  er = copysignf(er, z);
  return 0.5f * x * (1.0f + er);
}

__device__ __forceinline__ size_t remap_kv(int tok, int mode){
  // tok = bn*2816 + i*88 + j  ->  KP/VP row ((b*64+l)*264 + t)
  int bn = tok / 2816; int p = tok - bn*2816;
  int b = bn / 6, n = bn - b*6;
  int i = p / 88, j = p - i*88;
  int l, t;
  if (mode == 1){            // stage 1: _win(k, 4, 11)
    int jw = j / 11;
    l = (i >> 2)*8 + jw;
    t = n*44 + (i & 3)*11 + (j - jw*11);
  } else {                   // stage 2: _gridwin(k, 4, 11)
    l = (i & 7)*8 + (j & 7);
    t = n*44 + (i >> 3)*11 + (j >> 3);
  }
  return (size_t)((b*64 + l)*264 + t);
}

// ---------------- fused prep: wprep | geom | bevq2 (cembed inline) ----------
__global__ __launch_bounds__(128) void k_prep(
    const float* __restrict__ qkv, const float* __restrict__ wp,
    const float* __restrict__ wma, const float* __restrict__ wmb,
    const float* __restrict__ wfl, const float* __restrict__ wfp,
    unsigned short* __restrict__ Wt,
    const float* __restrict__ Iinv, const float* __restrict__ Einv,
    const float* __restrict__ Wimg, const float* __restrict__ Wcam,
    unsigned short* __restrict__ K1h,
    const float* __restrict__ gridp, const float* __restrict__ Wbev,
    const float* __restrict__ bbev, const float* __restrict__ x,
    const float* __restrict__ lg, const float* __restrict__ lb,
    unsigned short* __restrict__ Qh){
  int bid = blockIdx.x;
  if (bid < 64){
    // ---- weight prep: fp32 [k][n] -> bf16 [n][k]; Wmb split into 4 [128][128]
    const int sel[16]  = {0,0,0,0,0,0, 1,1, 2,2, 3,3,3,3, 4,5};
    const int soff[16] = {0,16384,32768,49152,65536,81920, 0,16384, 0,32768,
                          0,16384,32768,49152, 0,0};
    const int doff[16] = {0,16384,32768,49152,65536,81920, 98304,114688,
                          131072,163840, 196608,212992,229376,245760, 262144,278528};
    const int Ns[16]   = {128,128,128,128,128,128, 128,128, 256,256,
                          128,128,128,128, 128,128};
    const int trs[16]  = {1,1,1,1,1,1, 1,1, 1,1, 1,1,1,1, 0,0};
    int sg = bid >> 2, q = bid & 3;
    const float* srcs[6] = {qkv, wp, wma, wmb, wfl, wfp};
    const float* src = srcs[sel[sg]] + soff[sg];
    unsigned short* dst = Wt + doff[sg];
    int K = 128, N = Ns[sg];
    int quarter = (K*N) >> 2;
    for (int idx = q*quarter + threadIdx.x; idx < (q+1)*quarter; idx += 128){
      int n = idx / K, k = idx - n*K;
      float v = trs[sg] ? src[k*N + n] : src[idx];
      dst[idx] = f2bf(v);
    }
  } else if (bid < 4288){
    // ---- geom: img_embed normalized -> K1h bf16 (bn,p,c)
    int tile = bid - 64;
    int bn = tile / 352; int p0 = (tile - bn*352)*8;
    int xid = threadIdx.x >> 4, part = threadIdx.x & 15;
    int p = p0 + xid;
    int i = p / 88, j = p - i*88;
    float xs = (float)j * (480.0f/87.0f);
    float ys = (float)i * (224.0f/31.0f);
    const float* I = Iinv + bn*9;
    const float* E = Einv + bn*16;
    float c0 = I[0]*xs + I[1]*ys + I[2];
    float c1 = I[3]*xs + I[4]*ys + I[5];
    float c2 = I[6]*xs + I[7]*ys + I[8];
    float d0 = E[0]*c0 + E[1]*c1 + E[2]*c2 + E[3];
    float d1 = E[4]*c0 + E[5]*c1 + E[6]*c2 + E[7];
    float d2 = E[8]*c0 + E[9]*c1 + E[10]*c2 + E[11];
    float d3 = E[12]*c0 + E[13]*c1 + E[14]*c2 + E[15];
    float v[8]; float sq = 0.f;
    #pragma unroll
    for (int k=0;k<8;k++){
      int o = part*8 + k;
      const float* W = Wimg + o*4;
      const float* Wc = Wcam + o*4;
      float de = W[0]*d0 + W[1]*d1 + W[2]*d2 + W[3]*d3;
      float ce = Wc[0]*E[3] + Wc[1]*E[7] + Wc[2]*E[11] + Wc[3]*E[15];
      float vv = de - ce;
      v[k] = vv; sq = fmaf(vv, vv, sq);
    }
    #pragma unroll
    for (int off=8; off>0; off>>=1) sq += __shfl_xor(sq, off, 16);
    float rn = 1.0f / fmaxf(sqrtf(sq), 1e-12f);
    float o8[8];
    #pragma unroll
    for (int k=0;k<8;k++) o8[k] = v[k]*rn;
    store_bf16x8(K1h + (size_t)(bn*2816 + p)*128 + part*8, o8);
  } else {
    // ---- bevq2: query + stage-1 q LN, bf16 window-token order
    int tile = bid - 4288;
    int bn = tile >> 9; int pp0 = (tile & 511) << 3;
    int b = bn / 6, n = bn - b*6;
    int xid = threadIdx.x >> 4, part = threadIdx.x & 15;
    int pix = pp0 + xid;
    int h = pix >> 6, w = pix & 63;
    const float* E = Einv + bn*16;
    float g0 = gridp[pix], g1 = gridp[4096 + pix];
    float v[8]; float sq = 0.f;
    #pragma unroll
    for (int k=0;k<8;k++){
      int o = part*8 + k;
      const float* Wc = Wcam + o*4;
      float ce = Wc[0]*E[3] + Wc[1]*E[7] + Wc[2]*E[11] + Wc[3]*E[15];
      float we = Wbev[o*2]*g0 + Wbev[o*2+1]*g1 + bbev[o];
      float vv = we - ce;
      v[k] = vv; sq = fmaf(vv, vv, sq);
    }
    #pragma unroll
    for (int off=8; off>0; off>>=1) sq += __shfl_xor(sq, off, 16);
    float rn = 1.0f / fmaxf(sqrtf(sq), 1e-12f);
    const float* xp = x + ((size_t)b*128)*4096 + pix;
    float q[8]; float s=0.f, s2=0.f;
    #pragma unroll
    for (int k=0;k<8;k++){
      int o = part*8 + k;
      q[k] = fmaf(v[k], rn, xp[(size_t)o*4096]);
      s += q[k]; s2 = fmaf(q[k], q[k], s2);
    }
    #pragma unroll
    for (int off=8; off>0; off>>=1){ s += __shfl_xor(s, off, 16); s2 += __shfl_xor(s2, off, 16); }
    float mean = s*(1.f/128.f);
    float rstd = rsqrtf(fmaxf(s2*(1.f/128.f) - mean*mean, 0.f) + 1e-5f);
    int l = (h>>3)*8 + (w>>3);
    int t = n*64 + (h&7)*8 + (w&7);
    size_t row = (size_t)((b*64 + l)*384 + t);
    float o8[8];
    #pragma unroll
    for (int k=0;k<8;k++){
      int c = part*8 + k;
      o8[k] = fmaf((q[k]-mean)*rstd, lg[c], lb[c]);
    }
    store_bf16x8(Qh + row*128 + part*8, o8);
  }
}

// ---------------- merged conv (K role | V role), MT=64, single chunk --------
__global__ __launch_bounds__(256) void k_conv2(const float* __restrict__ feat,
    const float* __restrict__ gK, const float* __restrict__ bK,
    const unsigned short* __restrict__ WK, unsigned short* __restrict__ OK,
    const unsigned short* __restrict__ skipK,
    const float* __restrict__ gV, const float* __restrict__ bV,
    const unsigned short* __restrict__ WV, unsigned short* __restrict__ OV){
  constexpr int KP_ = 136;
  __shared__ unsigned short sW[128*KP_];
  __shared__ unsigned short sA[64*KP_];
  __shared__ float sg[128], sb[128];
  const int which = (blockIdx.x >= 528);
  const int bid = which ? blockIdx.x - 528 : blockIdx.x;
  const float* gg = which ? gV : gK;
  const float* bb = which ? bV : bK;
  const unsigned short* Wt = which ? WV : WK;
  unsigned short* OUT = which ? OV : OK;
  const int tid = threadIdx.x;
  for (int i = tid; i < 2048; i += 256){
    int n = i >> 4, k8 = (i & 15) << 3;
    *(short8*)&sW[n*KP_ + k8] = *(const short8*)(Wt + (size_t)n*128 + k8);
  }
  if (tid < 128){ sg[tid]=gg[tid]; sb[tid]=bb[tid]; }
  const int base = bid*64;
  const float RSQ = rsqrtf(1.0f + 1e-5f);
  {
    int prow = tid & 63, cseg = tid >> 6;
    int bn = base / 2816;
    int p = base - bn*2816 + prow;
    const float* fb = feat + ((size_t)bn*128 + cseg*32)*2816 + p;
    #pragma unroll
    for (int i=0;i<32;i+=2){
      int c = cseg*32 + i;
      float t0 = fb[(size_t)i*2816] * RSQ;
      float t1 = fb[(size_t)(i+1)*2816] * RSQ;
      float y0 = fmaxf(fmaf(t0, sg[c],   sb[c]),   0.f);
      float y1 = fmaxf(fmaf(t1, sg[c+1], sb[c+1]), 0.f);
      unsigned u = (unsigned)f2bf(y0) | ((unsigned)f2bf(y1) << 16);
      *(unsigned*)&sA[prow*KP_ + c] = u;
    }
  }
  __syncthreads();
  const int lane = tid & 63, wv = tid >> 6;
  const int lane15 = lane & 15, quad = lane >> 4;
  const int n0 = wv * 32;
  f32x4 acc[4][2];
  #pragma unroll
  for (int mt=0; mt<4; mt++){ acc[mt][0]=(f32x4)0.f; acc[mt][1]=(f32x4)0.f; }
  const unsigned short* aptr = sA + lane15*KP_ + quad*8;
  const unsigned short* bptr = sW + (size_t)(n0 + lane15)*KP_ + quad*8;
  #pragma unroll
  for (int kk=0; kk<4; kk++){
    short8 af[4], bf2[2];
    #pragma unroll
    for (int mt=0; mt<4; mt++) af[mt] = *(const short8*)(aptr + mt*16*KP_ + kk*32);
    bf2[0] = *(const short8*)(bptr + kk*32);
    bf2[1] = *(const short8*)(bptr + 16*KP_ + kk*32);
    #pragma unroll
    for (int mt=0; mt<4; mt++){
      acc[mt][0] = __builtin_amdgcn_mfma_f32_16x16x32_bf16(af[mt], bf2[0], acc[mt][0], 0,0,0);
      acc[mt][1] = __builtin_amdgcn_mfma_f32_16x16x32_bf16(af[mt], bf2[1], acc[mt][1], 0,0,0);
    }
  }
  __syncthreads();
  #pragma unroll
  for (int mt=0; mt<4; mt++){
    #pragma unroll
    for (int nt=0; nt<2; nt++){
      int col = n0 + nt*16 + lane15;
      #pragma unroll
      for (int r4=0; r4<4; r4++){
        int row = mt*16 + quad*4 + r4;
        float v = acc[mt][nt][r4];
        if (!which) v += bf2f(skipK[(size_t)(base+row)*128 + col]);
        sA[row*KP_ + col] = f2bf(v);
      }
    }
  }
  __syncthreads();
  for (int i = tid; i < 1024; i += 256){
    int row = i >> 4, seg = i & 15;
    *(short8*)(OUT + (size_t)(base+row)*128 + seg*8) = *(const short8*)&sA[row*KP_ + seg*8];
  }
}

// ---------------- generic 2-role KT=128 gemm, single chunk per block --------
struct GArg {
  const unsigned short* Xh; int ldx;
  const float* lg; const float* lb;
  const unsigned short* Wt; const float* bias;
  unsigned short* OUTH; int ldout; float oscale;
  int do_ln; int act; int outmode; int skip_mode;
  const float* skipf; const unsigned short* skiph; int ldskip;
};

template<int MT>
__global__ __launch_bounds__(256) void k_gemm2(GArg ga, GArg gb, int splitA){
  constexpr int KP_ = 136;
  constexpr int MTILES = MT / 16;
  constexpr int TPR = 256 / MT;
  constexpr int KPT = 128 / TPR;
  __shared__ unsigned short sW[128*KP_];
  __shared__ unsigned short sA[MT*KP_];
  __shared__ float sg[128], sb[128], sbias[128];
  const int which = ((int)blockIdx.x >= splitA);
  const GArg g = which ? gb : ga;
  const int bid = which ? blockIdx.x - splitA : blockIdx.x;
  const int base = bid * MT;
  const int tid = threadIdx.x;
  for (int i = tid; i < 2048; i += 256){
    int n = i >> 4, k8 = (i & 15) << 3;
    *(short8*)&sW[n*KP_ + k8] = *(const short8*)(g.Wt + (size_t)n*128 + k8);
  }
  if (tid < 128){
    if (g.do_ln){ sg[tid]=g.lg[tid]; sb[tid]=g.lb[tid]; }
    sbias[tid] = g.bias ? g.bias[tid] : 0.f;
  }
  {
    const int r = tid / TPR, part = tid % TPR;
    const unsigned short* src = g.Xh + (size_t)(base+r)*g.ldx + part*KPT;
    unsigned short* dst = sA + r*KP_ + part*KPT;
    if (!g.do_ln){
      #pragma unroll
      for (int k=0;k<KPT;k+=8) *(short8*)(dst+k) = *(const short8*)(src+k);
    } else {
      float v[KPT];
      #pragma unroll
      for (int k=0;k<KPT;k+=8){
        union { short8 s; unsigned short u[8]; } t;
        t.s = *(const short8*)(src+k);
        #pragma unroll
        for (int i2=0;i2<8;i2++) v[k+i2] = bf2f(t.u[i2]);
      }
      float s=0.f, s2=0.f;
      #pragma unroll
      for (int k=0;k<KPT;k++){ s += v[k]; s2 = fmaf(v[k],v[k],s2); }
      #pragma unroll
      for (int off=TPR/2; off>0; off>>=1){
        s += __shfl_xor(s, off, TPR); s2 += __shfl_xor(s2, off, TPR);
      }
      float mean = s * (1.f/128.f);
      float rstd = rsqrtf(fmaxf(s2*(1.f/128.f) - mean*mean, 0.f) + 1e-5f);
      #pragma unroll
      for (int k=0;k<KPT;k++){
        int c = part*KPT + k;
        v[k] = fmaf((v[k]-mean)*rstd, sg[c], sb[c]);
      }
      #pragma unroll
      for (int k=0;k<KPT;k+=8) store_bf16x8(dst+k, v+k);
    }
  }
  __syncthreads();
  const int lane = tid & 63, wv = tid >> 6;
  const int lane15 = lane & 15, quad = lane >> 4;
  const int n0 = wv * 32;
  f32x4 acc[MTILES][2];
  #pragma unroll
  for (int mt=0; mt<MTILES; mt++){ acc[mt][0]=(f32x4)0.f; acc[mt][1]=(f32x4)0.f; }
  const unsigned short* aptr = sA + lane15*KP_ + quad*8;
  const unsigned short* bptr = sW + (size_t)(n0 + lane15)*KP_ + quad*8;
  #pragma unroll
  for (int kk=0; kk<4; kk++){
    short8 af[MTILES], bf2[2];
    #pragma unroll
    for (int mt=0; mt<MTILES; mt++) af[mt] = *(const short8*)(aptr + mt*16*KP_ + kk*32);
    bf2[0] = *(const short8*)(bptr + kk*32);
    bf2[1] = *(const short8*)(bptr + 16*KP_ + kk*32);
    #pragma unroll
    for (int mt=0; mt<MTILES; mt++){
      acc[mt][0] = __builtin_amdgcn_mfma_f32_16x16x32_bf16(af[mt], bf2[0], acc[mt][0], 0,0,0);
      acc[mt][1] = __builtin_amdgcn_mfma_f32_16x16x32_bf16(af[mt], bf2[1], acc[mt][1], 0,0,0);
    }
  }
  __syncthreads();
  #pragma unroll
  for (int mt=0; mt<MTILES; mt++){
    #pragma unroll
    for (int nt=0; nt<2; nt++){
      int col = n0 + nt*16 + lane15;
      float bsv = sbias[col];
      #pragma unroll
      for (int r4=0; r4<4; r4++){
        int row = mt*16 + quad*4 + r4;
        int rrow = base + row;
        float v = acc[mt][nt][r4] + bsv;
        if (g.act) v = gelu_erf(v);
        if (g.skip_mode == 1){
          int bb = rrow >> 12, l = (rrow >> 6) & 63, pp = rrow & 63;
          int pix = (((l>>3)*8 + (pp>>3)) << 6) + (l&7)*8 + (pp&7);
          v += g.skipf[(size_t)bb*524288 + (size_t)col*4096 + pix];
        } else if (g.skip_mode == 2){
          v += bf2f(g.skiph[(size_t)rrow*g.ldskip + col]);
        }
        v *= g.oscale;
        sA[row*KP_ + col] = f2bf(v);
      }
    }
  }
  __syncthreads();
  for (int i = tid; i < MT*16; i += 256){
    int row = i >> 4, seg = i & 15;
    int rrow = base + row;
    size_t orow = g.outmode ? remap_kv(rrow, g.outmode) : (size_t)rrow;
    *(short8*)(g.OUTH + orow*(size_t)g.ldout + seg*8) = *(const short8*)&sA[row*KP_ + seg*8];
  }
}

// ---------------- KT=256 gemm (MB), fp32 accum over both k-halves -----------
__global__ __launch_bounds__(256) void k_gemm256(
    const unsigned short* __restrict__ Xh,           // rows ld 256
    const unsigned short* __restrict__ Wt1, const unsigned short* __restrict__ Wt2,
    const float* __restrict__ bias, unsigned short* __restrict__ OUTH,
    const unsigned short* __restrict__ skiph){
  constexpr int KP_ = 136;
  __shared__ unsigned short sW[128*KP_];
  __shared__ unsigned short sA[2*32*KP_];
  __shared__ float sbias[128];
  const int tid = threadIdx.x;
  const int base = blockIdx.x * 32;
  // stage A (both halves) + W half1
  {
    const int r = tid >> 3, part = tid & 7;      // 8 thr/row, 32 shorts each
    const unsigned short* src = Xh + (size_t)(base+r)*256 + part*32;
    unsigned short* dst = sA + (part>>2)*32*KP_ + r*KP_ + (part&3)*32;
    #pragma unroll
    for (int k=0;k<32;k+=8) *(short8*)(dst+k) = *(const short8*)(src+k);
  }
  for (int i = tid; i < 2048; i += 256){
    int n = i >> 4, k8 = (i & 15) << 3;
    *(short8*)&sW[n*KP_ + k8] = *(const short8*)(Wt1 + (size_t)n*128 + k8);
  }
  if (tid < 128) sbias[tid] = bias ? bias[tid] : 0.f;
  __syncthreads();
  const int lane = tid & 63, wv = tid >> 6;
  const int lane15 = lane & 15, quad = lane >> 4;
  const int n0 = wv * 32;
  f32x4 acc[2][2];
  acc[0][0]=(f32x4)0.f; acc[0][1]=(f32x4)0.f;
  acc[1][0]=(f32x4)0.f; acc[1][1]=(f32x4)0.f;
  #pragma unroll
  for (int half=0; half<2; half++){
    const unsigned short* aptr = sA + half*32*KP_ + lane15*KP_ + quad*8;
    const unsigned short* bptr = sW + (size_t)(n0 + lane15)*KP_ + quad*8;
    #pragma unroll
    for (int kk=0; kk<4; kk++){
      short8 a0 = *(const short8*)(aptr + kk*32);
      short8 a1 = *(const short8*)(aptr + 16*KP_ + kk*32);
      short8 b0 = *(const short8*)(bptr + kk*32);
      short8 b1 = *(const short8*)(bptr + 16*KP_ + kk*32);
      acc[0][0] = __builtin_amdgcn_mfma_f32_16x16x32_bf16(a0,b0,acc[0][0],0,0,0);
      acc[1][0] = __builtin_amdgcn_mfma_f32_16x16x32_bf16(a1,b0,acc[1][0],0,0,0);
      acc[0][1] = __builtin_amdgcn_mfma_f32_16x16x32_bf16(a0,b1,acc[0][1],0,0,0);
      acc[1][1] = __builtin_amdgcn_mfma_f32_16x16x32_bf16(a1,b1,acc[1][1],0,0,0);
    }
    if (half == 0){
      __syncthreads();     // done reading W half1
      for (int i = tid; i < 2048; i += 256){
        int n = i >> 4, k8 = (i & 15) << 3;
        *(short8*)&sW[n*KP_ + k8] = *(const short8*)(Wt2 + (size_t)n*128 + k8);
      }
      __syncthreads();
    }
  }
  __syncthreads();         // all mfma reads of sA done
  #pragma unroll
  for (int mt=0; mt<2; mt++){
    #pragma unroll
    for (int nt=0; nt<2; nt++){
      int col = n0 + nt*16 + lane15;
      float bsv = sbias[col];
      #pragma unroll
      for (int r4=0; r4<4; r4++){
        int row = mt*16 + quad*4 + r4;
        float v = acc[mt][nt][r4] + bsv + bf2f(skiph[(size_t)(base+row)*128 + col]);
        sA[row*KP_ + col] = f2bf(v);
      }
    }
  }
  __syncthreads();
  for (int i = tid; i < 512; i += 256){
    int row = i >> 4, seg = i & 15;
    *(short8*)(OUTH + (size_t)(base+row)*128 + seg*8) = *(const short8*)&sA[row*KP_ + seg*8];
  }
}

// ---------------- MFMA attention: one block per (b,l,head), 4 waves ---------
__global__ __launch_bounds__(256) void k_attn2(const unsigned short* __restrict__ QPh,
    const unsigned short* __restrict__ KPh, const unsigned short* __restrict__ VPh,
    unsigned short* __restrict__ AOh, int nrep, int nQ){
  __shared__ unsigned short Ksh[288*40];   // [key][32d + pad]
  __shared__ unsigned short Vt[32*296];    // [d][288key + pad]
  __shared__ unsigned short Psh[4*16*40];  // per-wave P tile
  __shared__ float rs[4*16];
  int hd = blockIdx.x & 3; int bl = blockIdx.x >> 2;
  size_t kvbase = (size_t)bl*264;
  int tid = threadIdx.x;
  for (int idx = tid; idx < 1056; idx += 256){     // K rows, vectorized
    int row = idx >> 2, seg = idx & 3;
    *(short8*)&Ksh[row*40 + seg*8] =
      *(const short8*)(KPh + (kvbase+row)*128 + hd*32 + seg*8);
  }
  for (int idx = tid; idx < 96; idx += 256){       // zero K pad rows
    int row = 264 + (idx>>2), seg = idx & 3;
    short8 z = {0,0,0,0,0,0,0,0};
    *(short8*)&Ksh[row*40 + seg*8] = z;
  }
  for (int idx = tid; idx < 1056; idx += 256){     // V transpose, vector reads
    int row = idx >> 2, seg = idx & 3;
    union { short8 s; unsigned short u[8]; } t;
    t.s = *(const short8*)(VPh + (kvbase+row)*128 + hd*32 + seg*8);
    #pragma unroll
    for (int i=0;i<8;i++) Vt[(seg*8+i)*296 + row] = t.u[i];
  }
  for (int idx = tid; idx < 384; idx += 256){      // zero V pad keys
    int d = idx / 12, kp = 264 + (idx % 12)*2;
    *(unsigned*)&Vt[d*296 + kp] = 0u;
  }
  __syncthreads();
  const int wv = tid >> 6, lane = tid & 63;
  const int lane15 = lane & 15, quad = lane >> 4;
  unsigned short* Pw = Psh + wv*640;
  float* rsw = rs + wv*16;
  short8 vfrag[9][2];
  #pragma unroll
  for (int kc=0; kc<9; kc++){
    vfrag[kc][0] = *(const short8*)&Vt[(lane15)*296      + kc*32 + quad*8];
    vfrag[kc][1] = *(const short8*)&Vt[(16+lane15)*296   + kc*32 + quad*8];
  }
  f32x4 macc0 = (f32x4)0.f, macc1 = (f32x4)0.f;
  for (int cam = 0; cam < nrep; cam++){
    int qrow = bl*nQ + (cam*4 + wv)*16 + lane15;
    short8 qf = *(const short8*)(QPh + (size_t)qrow*128 + hd*32 + quad*8);
    f32x4 oa0 = (f32x4)0.f, oa1 = (f32x4)0.f;
    float rsum = 0.f;
    #pragma unroll
    for (int kc=0; kc<9; kc++){
      #pragma unroll
      for (int sub=0; sub<2; sub++){
        int kt = kc*2 + sub;
        short8 kf = *(const short8*)&Ksh[(kt*16 + lane15)*40 + quad*8];
        f32x4 st = __builtin_amdgcn_mfma_f32_16x16x32_bf16(kf, qf, (f32x4)0.f, 0,0,0);
        int kbase = kt*16 + quad*4;
        float e0 = (kbase+0 < 264) ? __expf(st[0]) : 0.f;
        float e1 = (kbase+1 < 264) ? __expf(st[1]) : 0.f;
        float e2 = (kbase+2 < 264) ? __expf(st[2]) : 0.f;
        float e3 = (kbase+3 < 264) ? __expf(st[3]) : 0.f;
        rsum += (e0+e1)+(e2+e3);
        uint2 pk;
        pk.x = (unsigned)f2bf(e0) | ((unsigned)f2bf(e1) << 16);
        pk.y = (unsigned)f2bf(e2) | ((unsigned)f2bf(e3) << 16);
        *(uint2*)&Pw[lane15*40 + sub*16 + quad*4] = pk;
      }
      short8 pf = *(const short8*)&Pw[lane15*40 + quad*8];
      oa0 = __builtin_amdgcn_mfma_f32_16x16x32_bf16(pf, vfrag[kc][0], oa0, 0,0,0);
      oa1 = __builtin_amdgcn_mfma_f32_16x16x32_bf16(pf, vfrag[kc][1], oa1, 0,0,0);
    }
    rsum += __shfl_xor(rsum, 16);
    rsum += __shfl_xor(rsum, 32);
    if (lane < 16) rsw[lane] = rsum;
    f32x4 rv = *(f32x4*)&rsw[quad*4];
    #pragma unroll
    for (int r=0;r<4;r++){
      float inv = 1.f / rv[r];
      macc0[r] = fmaf(oa0[r], inv, macc0[r]);
      macc1[r] = fmaf(oa1[r], inv, macc1[r]);
    }
  }
  float sc = (nrep == 6) ? (1.f/6.f) : 1.f;
  int pixb = wv*16 + quad*4;
  #pragma unroll
  for (int r=0;r<4;r++){
    size_t rowo = ((size_t)(bl*64 + pixb + r))*128 + hd*32;
    AOh[rowo + lane15]      = f2bf(macc0[r]*sc);
    AOh[rowo + 16 + lane15] = f2bf(macc1[r]*sc);
  }
}

// ---------------- final LN (bf16 in) + transpose to (B,128,64,64) fp32 ------
__global__ __launch_bounds__(128) void k_final(const unsigned short* __restrict__ Xh,
    const float* __restrict__ g, const float* __restrict__ be,
    float* __restrict__ out){
  __shared__ float st[1024];
  __shared__ float sm[8], sr[8];
  int r0 = blockIdx.x*8;
  int b = r0 >> 12, l = (r0 >> 6) & 63, p0 = r0 & 63;
  int h = (l >> 3)*8 + (p0 >> 3);
  int wbase = (l & 7)*8;
  {
    union { short8 s; unsigned short u[8]; } t;
    t.s = *(const short8*)(Xh + (size_t)r0*128 + threadIdx.x*8);
    #pragma unroll
    for (int i=0;i<8;i++) st[threadIdx.x*8 + i] = bf2f(t.u[i]);
  }
  __syncthreads();
  int xid = threadIdx.x >> 4, part = threadIdx.x & 15;
  float s=0.f, s2=0.f;
  #pragma unroll
  for (int k=0;k<8;k++){
    float v = st[xid*128 + part*8 + k];
    s += v; s2 = fmaf(v,v,s2);
  }
  #pragma unroll
  for (int off=8; off>0; off>>=1){ s += __shfl_xor(s, off, 16); s2 += __shfl_xor(s2, off, 16); }
  if (part == 0){
    float mean = s*(1.f/128.f);
    sm[xid] = mean;
    sr[xid] = rsqrtf(fmaxf(s2*(1.f/128.f) - mean*mean, 0.f) + 1e-5f);
  }
  __syncthreads();
  int o = threadIdx.x;
  float go = g[o], bo = be[o];
  size_t obase = ((size_t)(b*128 + o))*4096 + h*64 + wbase;
  float res[8];
  #pragma unroll
  for (int x=0;x<8;x++) res[x] = fmaf((st[x*128+o]-sm[x])*sr[x], go, bo);
  *(float4*)&out[obase]   = make_float4(res[0],res[1],res[2],res[3]);
  *(float4*)&out[obase+4] = make_float4(res[4],res[5],res[6],res[7]);
}

extern "C" void kernel_launch(void* const* d_in, const int* in_sizes, int n_in,
                              void* d_out, int out_size, void* d_ws, size_t ws_size,
                              hipStream_t stream) {
  (void)in_sizes; (void)n_in; (void)out_size; (void)ws_size;
  const float* x     = (const float*)d_in[1];
  const float* gridp = (const float*)d_in[2];
  const float* feat  = (const float*)d_in[3];
  const float* Iinv  = (const float*)d_in[4];
  const float* Einv  = (const float*)d_in[5];
  const float* gfl   = (const float*)d_in[6];
  const float* bfl   = (const float*)d_in[7];
  const float* Wfl   = (const float*)d_in[8];
  const float* gfp   = (const float*)d_in[9];
  const float* bfp   = (const float*)d_in[10];
  const float* Wfp   = (const float*)d_in[11];
  const float* Wbev  = (const float*)d_in[12];
  const float* bbev  = (const float*)d_in[13];
  const float* Wimg  = (const float*)d_in[14];
  const float* Wcam  = (const float*)d_in[15];
  const float* alng  = (const float*)d_in[16];
  const float* alnb  = (const float*)d_in[17];
  const float* aWqkv = (const float*)d_in[18];
  const float* abqkv = (const float*)d_in[19];
  const float* aWp   = (const float*)d_in[20];
  const float* abp   = (const float*)d_in[21];
  const float* png   = (const float*)d_in[22];
  const float* pnb   = (const float*)d_in[23];
  const float* Wma   = (const float*)d_in[24];
  const float* bma   = (const float*)d_in[25];
  const float* Wmb   = (const float*)d_in[26];
  const float* bmb   = (const float*)d_in[27];
  const float* postg = (const float*)d_in[28];
  const float* postb = (const float*)d_in[29];
  float* out = (float*)d_out;
  float* ws  = (float*)d_ws;
  const float QSC = 0.17677669529663687f;   // 32^-0.5 folded into q projections

  unsigned short* Wt  = (unsigned short*)(ws + 2048);    // 294912 ush
  unsigned short* K1h = (unsigned short*)(ws + 149504);  // 33792x128
  unsigned short* V1h = K1h + 4325376;
  unsigned short* KPh = V1h + 4325376;                   // 128win x 264 x 128
  unsigned short* VPh = KPh + 4325376;
  unsigned short* QPh = VPh + 4325376;                   // 49152x128
  unsigned short* Qbh = QPh + 6291456;                   // 49152x128
  unsigned short* AOh = Qbh + 6291456;                   // 8192x128
  unsigned short* CURh= AOh + 1048576;
  unsigned short* Hh  = CURh + 1048576;                  // 8192x256
  unsigned short* Q1h = Hh + 2097152;
  unsigned short* Q2h = Q1h + 1048576;

  unsigned short* WtQ1 = Wt;            unsigned short* WtK1 = Wt + 16384;
  unsigned short* WtV1 = Wt + 32768;    unsigned short* WtQ2 = Wt + 49152;
  unsigned short* WtK2 = Wt + 65536;    unsigned short* WtV2 = Wt + 81920;
  unsigned short* WtP1 = Wt + 98304;    unsigned short* WtP2 = Wt + 114688;
  unsigned short* WtMA1 = Wt + 131072;  unsigned short* WtMA2 = Wt + 163840;
  unsigned short* WtMB1a = Wt + 196608; unsigned short* WtMB1b = Wt + 212992;
  unsigned short* WtMB2a = Wt + 229376; unsigned short* WtMB2b = Wt + 245760;
  unsigned short* WtFL = Wt + 262144;   unsigned short* WtFP = Wt + 278528;

  GArg Z{}; Z.oscale = 1.f;

  // 1) fused prep
  k_prep<<<10432, 128, 0, stream>>>(aWqkv, aWp, Wma, Wmb, Wfl, Wfp, Wt,
      Iinv, Einv, Wimg, Wcam, K1h, gridp, Wbev, bbev, x, alng, alnb, Qbh);

  // 2) conv K+V merged
  k_conv2<<<1056, 256, 0, stream>>>(feat, gfp, bfp, WtFP, K1h, K1h,
                                    gfl, bfl, WtFL, V1h);

  // 3) stage-1 Q projection (M=49152)
  {
    GArg a = Z;
    a.Xh=Qbh; a.ldx=128; a.Wt=WtQ1; a.bias=abqkv; a.OUTH=QPh; a.ldout=128;
    a.oscale=QSC;
    k_gemm2<64><<<768, 256, 0, stream>>>(a, a, 768);
  }
  // 4) stage-1 K+V projection merged
  {
    GArg a = Z, b = Z;
    a.Xh=K1h; a.ldx=128; a.do_ln=1; a.lg=alng+128; a.lb=alnb+128;
    a.Wt=WtK1; a.bias=abqkv+128; a.OUTH=KPh; a.ldout=128; a.outmode=1;
    b = a; b.Xh=V1h; b.lg=alng+256; b.lb=alnb+256; b.Wt=WtV1;
    b.bias=abqkv+256; b.OUTH=VPh;
    k_gemm2<64><<<1056, 256, 0, stream>>>(a, b, 528);
  }
  // 5) stage-1 attention
  k_attn2<<<512, 256, 0, stream>>>(QPh, KPh, VPh, AOh, 6, 384);
  // 6) stage-1 out-projection + x skip
  {
    GArg a = Z;
    a.Xh=AOh; a.ldx=128; a.Wt=WtP1; a.bias=abp; a.OUTH=CURh; a.ldout=128;
    a.skip_mode=1; a.skipf=x;
    k_gemm2<32><<<256, 256, 0, stream>>>(a, a, 256);
  }
  // 7) stage-1 MLP up (both halves merged)
  {
    GArg a = Z, b = Z;
    a.Xh=CURh; a.ldx=128; a.do_ln=1; a.lg=png; a.lb=pnb;
    a.Wt=WtMA1; a.bias=bma; a.OUTH=Hh; a.ldout=256; a.act=1;
    b = a; b.Wt=WtMA1+16384; b.bias=bma+128; b.OUTH=Hh+128;
    k_gemm2<32><<<512, 256, 0, stream>>>(a, b, 256);
  }
  // 8) stage-1 MLP down (KT=256) + CUR skip
  k_gemm256<<<256, 256, 0, stream>>>(Hh, WtMB1a, WtMB1b, bmb, Q1h, CURh);

  // 9) stage-2 Q projection
  {
    GArg a = Z;
    a.Xh=Q1h; a.ldx=128; a.do_ln=1; a.lg=alng+384; a.lb=alnb+384;
    a.Wt=WtQ2; a.bias=abqkv+384; a.OUTH=QPh; a.ldout=128; a.oscale=QSC;
    k_gemm2<32><<<256, 256, 0, stream>>>(a, a, 256);
  }
  // 10) stage-2 K+V projection merged
  {
    GArg a = Z, b = Z;
    a.Xh=K1h; a.ldx=128; a.do_ln=1; a.lg=alng+512; a.lb=alnb+512;
    a.Wt=WtK2; a.bias=abqkv+512; a.OUTH=KPh; a.ldout=128; a.outmode=2;
    b = a; b.Xh=V1h; b.lg=alng+640; b.lb=alnb+640; b.Wt=WtV2;
    b.bias=abqkv+640; b.OUTH=VPh;
    k_gemm2<64><<<1056, 256, 0, stream>>>(a, b, 528);
  }
  // 11) stage-2 attention
  k_attn2<<<512, 256, 0, stream>>>(QPh, KPh, VPh, AOh, 1, 64);
  // 12) stage-2 out-projection + Q1 skip
  {
    GArg a = Z;
    a.Xh=AOh; a.ldx=128; a.Wt=WtP2; a.bias=abp+128; a.OUTH=CURh; a.ldout=128;
    a.skip_mode=2; a.skiph=Q1h; a.ldskip=128;
    k_gemm2<32><<<256, 256, 0, stream>>>(a, a, 256);
  }
  // 13) stage-2 MLP up
  {
    GArg a = Z, b = Z;
    a.Xh=CURh; a.ldx=128; a.do_ln=1; a.lg=png+128; a.lb=pnb+128;
    a.Wt=WtMA2; a.bias=bma+256; a.OUTH=Hh; a.ldout=256; a.act=1;
    b = a; b.Wt=WtMA2+16384; b.bias=bma+384; b.OUTH=Hh+128;
    k_gemm2<32><<<512, 256, 0, stream>>>(a, b, 256);
  }
  // 14) stage-2 MLP down + CUR skip
  k_gemm256<<<256, 256, 0, stream>>>(Hh, WtMB2a, WtMB2b, bmb+128, Q2h, CURh);

  // 15) final LN + transpose
  k_final<<<1024, 128, 0, stream>>>(Q2h, postg, postb, out);
}

// Round 7
// 302.263 us; speedup vs baseline: 1.6674x; 1.0424x over previous
//
#include <hip/hip_runtime.h>
#include <math.h>

// CrossViewSwapAttention forward. Round 7: coalesced x-staging in prep
// (LDS transpose tile), Q/K/V projections merged into one 3-role dispatch
// per stage (15 -> 13 dispatches).
// B=2 N=6 H=W=64 FH=32 FW=88 DIM=128 HEADS=4 DH=32 QW=8x8 KW=4x11

typedef __attribute__((ext_vector_type(8))) short short8;
typedef __attribute__((ext_vector_type(4))) float f32x4;

__device__ __forceinline__ unsigned short f2bf(float f){
  union { float f; unsigned u; } v; v.f = f;
  unsigned r = v.u + 0x7FFF + ((v.u >> 16) & 1);   // RNE
  return (unsigned short)(r >> 16);
}
__device__ __forceinline__ float bf2f(unsigned short h){
  union { unsigned u; float f; } v; v.u = ((unsigned)h) << 16; return v.f;
}
__device__ __forceinline__ void store_bf16x8(unsigned short* p, const float* v){
  union { short8 s8; unsigned short u[8]; } u;
  #pragma unroll
  for (int i=0;i<8;i++) u.u[i] = f2bf(v[i]);
  *(short8*)p = u.s8;
}

// gelu(x) = 0.5 x (1 + erf(x/sqrt2)); erf via A&S 7.1.26, |err| <= 1.5e-7.
__device__ __forceinline__ float gelu_erf(float x){
  float z = x * 0.70710678118654752f;
  float a = fabsf(z);
  float t = 1.0f / fmaf(0.3275911f, a, 1.0f);
  float p = t*(0.254829592f + t*(-0.284496736f + t*(1.421413741f +
            t*(-1.453152027f + t*1.061405429f))));
  float er = 1.0f - p*__expf(-a*a);
  er = copysignf(er, z);
  return 0.5f * x * (1.0f + er);
}

__device__ __forceinline__ size_t remap_kv(int tok, int mode){
  // tok = bn*2816 + i*88 + j  ->  KP/VP row ((b*64+l)*264 + t)
  int bn = tok / 2816; int p = tok - bn*2816;
  int b = bn / 6, n = bn - b*6;
  int i = p / 88, j = p - i*88;
  int l, t;
  if (mode == 1){            // stage 1: _win(k, 4, 11)
    int jw = j / 11;
    l = (i >> 2)*8 + jw;
    t = n*44 + (i & 3)*11 + (j - jw*11);
  } else {                   // stage 2: _gridwin(k, 4, 11)
    l = (i & 7)*8 + (j & 7);
    t = n*44 + (i >> 3)*11 + (j >> 3);
  }
  return (size_t)((b*64 + l)*264 + t);
}

// ---------------- fused prep: wprep | geom | bevq2 (cembed inline) ----------
__global__ __launch_bounds__(128) void k_prep(
    const float* __restrict__ qkv, const float* __restrict__ wp,
    const float* __restrict__ wma, const float* __restrict__ wmb,
    const float* __restrict__ wfl, const float* __restrict__ wfp,
    unsigned short* __restrict__ Wt,
    const float* __restrict__ Iinv, const float* __restrict__ Einv,
    const float* __restrict__ Wimg, const float* __restrict__ Wcam,
    unsigned short* __restrict__ K1h,
    const float* __restrict__ gridp, const float* __restrict__ Wbev,
    const float* __restrict__ bbev, const float* __restrict__ x,
    const float* __restrict__ lg, const float* __restrict__ lb,
    unsigned short* __restrict__ Qh){
  __shared__ float sx[128][9];        // x tile (channel-major), bevq2 branch
  int bid = blockIdx.x;
  if (bid < 64){
    // ---- weight prep: fp32 [k][n] -> bf16 [n][k]; Wmb split into 4 [128][128]
    const int sel[16]  = {0,0,0,0,0,0, 1,1, 2,2, 3,3,3,3, 4,5};
    const int soff[16] = {0,16384,32768,49152,65536,81920, 0,16384, 0,32768,
                          0,16384,32768,49152, 0,0};
    const int doff[16] = {0,16384,32768,49152,65536,81920, 98304,114688,
                          131072,163840, 196608,212992,229376,245760, 262144,278528};
    const int Ns[16]   = {128,128,128,128,128,128, 128,128, 256,256,
                          128,128,128,128, 128,128};
    const int trs[16]  = {1,1,1,1,1,1, 1,1, 1,1, 1,1,1,1, 0,0};
    int sg = bid >> 2, q = bid & 3;
    const float* srcs[6] = {qkv, wp, wma, wmb, wfl, wfp};
    const float* src = srcs[sel[sg]] + soff[sg];
    unsigned short* dst = Wt + doff[sg];
    int K = 128, N = Ns[sg];
    int quarter = (K*N) >> 2;
    for (int idx = q*quarter + threadIdx.x; idx < (q+1)*quarter; idx += 128){
      int n = idx / K, k = idx - n*K;
      float v = trs[sg] ? src[k*N + n] : src[idx];
      dst[idx] = f2bf(v);
    }
  } else if (bid < 4288){
    // ---- geom: img_embed normalized -> K1h bf16 (bn,p,c)
    int tile = bid - 64;
    int bn = tile / 352; int p0 = (tile - bn*352)*8;
    int xid = threadIdx.x >> 4, part = threadIdx.x & 15;
    int p = p0 + xid;
    int i = p / 88, j = p - i*88;
    float xs = (float)j * (480.0f/87.0f);
    float ys = (float)i * (224.0f/31.0f);
    const float* I = Iinv + bn*9;
    const float* E = Einv + bn*16;
    float c0 = I[0]*xs + I[1]*ys + I[2];
    float c1 = I[3]*xs + I[4]*ys + I[5];
    float c2 = I[6]*xs + I[7]*ys + I[8];
    float d0 = E[0]*c0 + E[1]*c1 + E[2]*c2 + E[3];
    float d1 = E[4]*c0 + E[5]*c1 + E[6]*c2 + E[7];
    float d2 = E[8]*c0 + E[9]*c1 + E[10]*c2 + E[11];
    float d3 = E[12]*c0 + E[13]*c1 + E[14]*c2 + E[15];
    float v[8]; float sq = 0.f;
    #pragma unroll
    for (int k=0;k<8;k++){
      int o = part*8 + k;
      const float* W = Wimg + o*4;
      const float* Wc = Wcam + o*4;
      float de = W[0]*d0 + W[1]*d1 + W[2]*d2 + W[3]*d3;
      float ce = Wc[0]*E[3] + Wc[1]*E[7] + Wc[2]*E[11] + Wc[3]*E[15];
      float vv = de - ce;
      v[k] = vv; sq = fmaf(vv, vv, sq);
    }
    #pragma unroll
    for (int off=8; off>0; off>>=1) sq += __shfl_xor(sq, off, 16);
    float rn = 1.0f / fmaxf(sqrtf(sq), 1e-12f);
    float o8[8];
    #pragma unroll
    for (int k=0;k<8;k++) o8[k] = v[k]*rn;
    store_bf16x8(K1h + (size_t)(bn*2816 + p)*128 + part*8, o8);
  } else {
    // ---- bevq2: query + stage-1 q LN, bf16 window-token order
    int tile = bid - 4288;
    int bn = tile >> 9; int pp0 = (tile & 511) << 3;
    int b = bn / 6, n = bn - b*6;
    // coalesced x stage: thread = channel, 8 consecutive w within one h-row
    {
      const float* xr = x + (size_t)b*524288 + (size_t)threadIdx.x*4096 + pp0;
      float4 a0 = *(const float4*)xr;
      float4 a1 = *(const float4*)(xr + 4);
      sx[threadIdx.x][0]=a0.x; sx[threadIdx.x][1]=a0.y;
      sx[threadIdx.x][2]=a0.z; sx[threadIdx.x][3]=a0.w;
      sx[threadIdx.x][4]=a1.x; sx[threadIdx.x][5]=a1.y;
      sx[threadIdx.x][6]=a1.z; sx[threadIdx.x][7]=a1.w;
    }
    __syncthreads();
    int xid = threadIdx.x >> 4, part = threadIdx.x & 15;
    int pix = pp0 + xid;
    int h = pix >> 6, w = pix & 63;
    const float* E = Einv + bn*16;
    float g0 = gridp[pix], g1 = gridp[4096 + pix];
    float v[8]; float sq = 0.f;
    #pragma unroll
    for (int k=0;k<8;k++){
      int o = part*8 + k;
      const float* Wc = Wcam + o*4;
      float ce = Wc[0]*E[3] + Wc[1]*E[7] + Wc[2]*E[11] + Wc[3]*E[15];
      float we = Wbev[o*2]*g0 + Wbev[o*2+1]*g1 + bbev[o];
      float vv = we - ce;
      v[k] = vv; sq = fmaf(vv, vv, sq);
    }
    #pragma unroll
    for (int off=8; off>0; off>>=1) sq += __shfl_xor(sq, off, 16);
    float rn = 1.0f / fmaxf(sqrtf(sq), 1e-12f);
    float q[8]; float s=0.f, s2=0.f;
    #pragma unroll
    for (int k=0;k<8;k++){
      q[k] = fmaf(v[k], rn, sx[part*8+k][xid]);
      s += q[k]; s2 = fmaf(q[k], q[k], s2);
    }
    #pragma unroll
    for (int off=8; off>0; off>>=1){ s += __shfl_xor(s, off, 16); s2 += __shfl_xor(s2, off, 16); }
    float mean = s*(1.f/128.f);
    float rstd = rsqrtf(fmaxf(s2*(1.f/128.f) - mean*mean, 0.f) + 1e-5f);
    int l = (h>>3)*8 + (w>>3);
    int t = n*64 + (h&7)*8 + (w&7);
    size_t row = (size_t)((b*64 + l)*384 + t);
    float o8[8];
    #pragma unroll
    for (int k=0;k<8;k++){
      int c = part*8 + k;
      o8[k] = fmaf((q[k]-mean)*rstd, lg[c], lb[c]);
    }
    store_bf16x8(Qh + row*128 + part*8, o8);
  }
}

// ---------------- merged conv (K role | V role), MT=64, single chunk --------
__global__ __launch_bounds__(256) void k_conv2(const float* __restrict__ feat,
    const float* __restrict__ gK, const float* __restrict__ bK,
    const unsigned short* __restrict__ WK, unsigned short* __restrict__ OK,
    const unsigned short* __restrict__ skipK,
    const float* __restrict__ gV, const float* __restrict__ bV,
    const unsigned short* __restrict__ WV, unsigned short* __restrict__ OV){
  constexpr int KP_ = 136;
  __shared__ unsigned short sW[128*KP_];
  __shared__ unsigned short sA[64*KP_];
  __shared__ float sg[128], sb[128];
  const int which = (blockIdx.x >= 528);
  const int bid = which ? blockIdx.x - 528 : blockIdx.x;
  const float* gg = which ? gV : gK;
  const float* bb = which ? bV : bK;
  const unsigned short* Wt = which ? WV : WK;
  unsigned short* OUT = which ? OV : OK;
  const int tid = threadIdx.x;
  for (int i = tid; i < 2048; i += 256){
    int n = i >> 4, k8 = (i & 15) << 3;
    *(short8*)&sW[n*KP_ + k8] = *(const short8*)(Wt + (size_t)n*128 + k8);
  }
  if (tid < 128){ sg[tid]=gg[tid]; sb[tid]=bb[tid]; }
  const int base = bid*64;
  const float RSQ = rsqrtf(1.0f + 1e-5f);
  {
    int prow = tid & 63, cseg = tid >> 6;
    int bn = base / 2816;
    int p = base - bn*2816 + prow;
    const float* fb = feat + ((size_t)bn*128 + cseg*32)*2816 + p;
    #pragma unroll
    for (int i=0;i<32;i+=2){
      int c = cseg*32 + i;
      float t0 = fb[(size_t)i*2816] * RSQ;
      float t1 = fb[(size_t)(i+1)*2816] * RSQ;
      float y0 = fmaxf(fmaf(t0, sg[c],   sb[c]),   0.f);
      float y1 = fmaxf(fmaf(t1, sg[c+1], sb[c+1]), 0.f);
      unsigned u = (unsigned)f2bf(y0) | ((unsigned)f2bf(y1) << 16);
      *(unsigned*)&sA[prow*KP_ + c] = u;
    }
  }
  __syncthreads();
  const int lane = tid & 63, wv = tid >> 6;
  const int lane15 = lane & 15, quad = lane >> 4;
  const int n0 = wv * 32;
  f32x4 acc[4][2];
  #pragma unroll
  for (int mt=0; mt<4; mt++){ acc[mt][0]=(f32x4)0.f; acc[mt][1]=(f32x4)0.f; }
  const unsigned short* aptr = sA + lane15*KP_ + quad*8;
  const unsigned short* bptr = sW + (size_t)(n0 + lane15)*KP_ + quad*8;
  #pragma unroll
  for (int kk=0; kk<4; kk++){
    short8 af[4], bf2[2];
    #pragma unroll
    for (int mt=0; mt<4; mt++) af[mt] = *(const short8*)(aptr + mt*16*KP_ + kk*32);
    bf2[0] = *(const short8*)(bptr + kk*32);
    bf2[1] = *(const short8*)(bptr + 16*KP_ + kk*32);
    #pragma unroll
    for (int mt=0; mt<4; mt++){
      acc[mt][0] = __builtin_amdgcn_mfma_f32_16x16x32_bf16(af[mt], bf2[0], acc[mt][0], 0,0,0);
      acc[mt][1] = __builtin_amdgcn_mfma_f32_16x16x32_bf16(af[mt], bf2[1], acc[mt][1], 0,0,0);
    }
  }
  __syncthreads();
  #pragma unroll
  for (int mt=0; mt<4; mt++){
    #pragma unroll
    for (int nt=0; nt<2; nt++){
      int col = n0 + nt*16 + lane15;
      #pragma unroll
      for (int r4=0; r4<4; r4++){
        int row = mt*16 + quad*4 + r4;
        float v = acc[mt][nt][r4];
        if (!which) v += bf2f(skipK[(size_t)(base+row)*128 + col]);
        sA[row*KP_ + col] = f2bf(v);
      }
    }
  }
  __syncthreads();
  for (int i = tid; i < 1024; i += 256){
    int row = i >> 4, seg = i & 15;
    *(short8*)(OUT + (size_t)(base+row)*128 + seg*8) = *(const short8*)&sA[row*KP_ + seg*8];
  }
}

// ---------------- generic 3-role KT=128 gemm, single chunk per block --------
struct GArg {
  const unsigned short* Xh; int ldx;
  const float* lg; const float* lb;
  const unsigned short* Wt; const float* bias;
  unsigned short* OUTH; int ldout; float oscale;
  int do_ln; int act; int outmode; int skip_mode;
  const float* skipf; const unsigned short* skiph; int ldskip;
};

template<int MT>
__global__ __launch_bounds__(256) void k_gemm3(GArg ga, GArg gb, GArg gc,
                                               int s1, int s2){
  constexpr int KP_ = 136;
  constexpr int MTILES = MT / 16;
  constexpr int TPR = 256 / MT;
  constexpr int KPT = 128 / TPR;
  __shared__ unsigned short sW[128*KP_];
  __shared__ unsigned short sA[MT*KP_];
  __shared__ float sg[128], sb[128], sbias[128];
  const int b0 = (int)blockIdx.x;
  const GArg g = (b0 < s1) ? ga : (b0 < s2) ? gb : gc;
  const int bid = (b0 < s1) ? b0 : (b0 < s2) ? b0 - s1 : b0 - s2;
  const int base = bid * MT;
  const int tid = threadIdx.x;
  for (int i = tid; i < 2048; i += 256){
    int n = i >> 4, k8 = (i & 15) << 3;
    *(short8*)&sW[n*KP_ + k8] = *(const short8*)(g.Wt + (size_t)n*128 + k8);
  }
  if (tid < 128){
    if (g.do_ln){ sg[tid]=g.lg[tid]; sb[tid]=g.lb[tid]; }
    sbias[tid] = g.bias ? g.bias[tid] : 0.f;
  }
  {
    const int r = tid / TPR, part = tid % TPR;
    const unsigned short* src = g.Xh + (size_t)(base+r)*g.ldx + part*KPT;
    unsigned short* dst = sA + r*KP_ + part*KPT;
    if (!g.do_ln){
      #pragma unroll
      for (int k=0;k<KPT;k+=8) *(short8*)(dst+k) = *(const short8*)(src+k);
    } else {
      float v[KPT];
      #pragma unroll
      for (int k=0;k<KPT;k+=8){
        union { short8 s; unsigned short u[8]; } t;
        t.s = *(const short8*)(src+k);
        #pragma unroll
        for (int i2=0;i2<8;i2++) v[k+i2] = bf2f(t.u[i2]);
      }
      float s=0.f, s2=0.f;
      #pragma unroll
      for (int k=0;k<KPT;k++){ s += v[k]; s2 = fmaf(v[k],v[k],s2); }
      #pragma unroll
      for (int off=TPR/2; off>0; off>>=1){
        s += __shfl_xor(s, off, TPR); s2 += __shfl_xor(s2, off, TPR);
      }
      float mean = s * (1.f/128.f);
      float rstd = rsqrtf(fmaxf(s2*(1.f/128.f) - mean*mean, 0.f) + 1e-5f);
      #pragma unroll
      for (int k=0;k<KPT;k++){
        int c = part*KPT + k;
        v[k] = fmaf((v[k]-mean)*rstd, sg[c], sb[c]);
      }
      #pragma unroll
      for (int k=0;k<KPT;k+=8) store_bf16x8(dst+k, v+k);
    }
  }
  __syncthreads();
  const int lane = tid & 63, wv = tid >> 6;
  const int lane15 = lane & 15, quad = lane >> 4;
  const int n0 = wv * 32;
  f32x4 acc[MTILES][2];
  #pragma unroll
  for (int mt=0; mt<MTILES; mt++){ acc[mt][0]=(f32x4)0.f; acc[mt][1]=(f32x4)0.f; }
  const unsigned short* aptr = sA + lane15*KP_ + quad*8;
  const unsigned short* bptr = sW + (size_t)(n0 + lane15)*KP_ + quad*8;
  #pragma unroll
  for (int kk=0; kk<4; kk++){
    short8 af[MTILES], bf2[2];
    #pragma unroll
    for (int mt=0; mt<MTILES; mt++) af[mt] = *(const short8*)(aptr + mt*16*KP_ + kk*32);
    bf2[0] = *(const short8*)(bptr + kk*32);
    bf2[1] = *(const short8*)(bptr + 16*KP_ + kk*32);
    #pragma unroll
    for (int mt=0; mt<MTILES; mt++){
      acc[mt][0] = __builtin_amdgcn_mfma_f32_16x16x32_bf16(af[mt], bf2[0], acc[mt][0], 0,0,0);
      acc[mt][1] = __builtin_amdgcn_mfma_f32_16x16x32_bf16(af[mt], bf2[1], acc[mt][1], 0,0,0);
    }
  }
  __syncthreads();
  #pragma unroll
  for (int mt=0; mt<MTILES; mt++){
    #pragma unroll
    for (int nt=0; nt<2; nt++){
      int col = n0 + nt*16 + lane15;
      float bsv = sbias[col];
      #pragma unroll
      for (int r4=0; r4<4; r4++){
        int row = mt*16 + quad*4 + r4;
        int rrow = base + row;
        float v = acc[mt][nt][r4] + bsv;
        if (g.act) v = gelu_erf(v);
        if (g.skip_mode == 1){
          int bb = rrow >> 12, l = (rrow >> 6) & 63, pp = rrow & 63;
          int pix = (((l>>3)*8 + (pp>>3)) << 6) + (l&7)*8 + (pp&7);
          v += g.skipf[(size_t)bb*524288 + (size_t)col*4096 + pix];
        } else if (g.skip_mode == 2){
          v += bf2f(g.skiph[(size_t)rrow*g.ldskip + col]);
        }
        v *= g.oscale;
        sA[row*KP_ + col] = f2bf(v);
      }
    }
  }
  __syncthreads();
  for (int i = tid; i < MT*16; i += 256){
    int row = i >> 4, seg = i & 15;
    int rrow = base + row;
    size_t orow = g.outmode ? remap_kv(rrow, g.outmode) : (size_t)rrow;
    *(short8*)(g.OUTH + orow*(size_t)g.ldout + seg*8) = *(const short8*)&sA[row*KP_ + seg*8];
  }
}

// ---------------- KT=256 gemm (MB), fp32 accum over both k-halves -----------
__global__ __launch_bounds__(256) void k_gemm256(
    const unsigned short* __restrict__ Xh,           // rows ld 256
    const unsigned short* __restrict__ Wt1, const unsigned short* __restrict__ Wt2,
    const float* __restrict__ bias, unsigned short* __restrict__ OUTH,
    const unsigned short* __restrict__ skiph){
  constexpr int KP_ = 136;
  __shared__ unsigned short sW[128*KP_];
  __shared__ unsigned short sA[2*32*KP_];
  __shared__ float sbias[128];
  const int tid = threadIdx.x;
  const int base = blockIdx.x * 32;
  {
    const int r = tid >> 3, part = tid & 7;      // 8 thr/row, 32 shorts each
    const unsigned short* src = Xh + (size_t)(base+r)*256 + part*32;
    unsigned short* dst = sA + (part>>2)*32*KP_ + r*KP_ + (part&3)*32;
    #pragma unroll
    for (int k=0;k<32;k+=8) *(short8*)(dst+k) = *(const short8*)(src+k);
  }
  for (int i = tid; i < 2048; i += 256){
    int n = i >> 4, k8 = (i & 15) << 3;
    *(short8*)&sW[n*KP_ + k8] = *(const short8*)(Wt1 + (size_t)n*128 + k8);
  }
  if (tid < 128) sbias[tid] = bias ? bias[tid] : 0.f;
  __syncthreads();
  const int lane = tid & 63, wv = tid >> 6;
  const int lane15 = lane & 15, quad = lane >> 4;
  const int n0 = wv * 32;
  f32x4 acc[2][2];
  acc[0][0]=(f32x4)0.f; acc[0][1]=(f32x4)0.f;
  acc[1][0]=(f32x4)0.f; acc[1][1]=(f32x4)0.f;
  #pragma unroll
  for (int half=0; half<2; half++){
    const unsigned short* aptr = sA + half*32*KP_ + lane15*KP_ + quad*8;
    const unsigned short* bptr = sW + (size_t)(n0 + lane15)*KP_ + quad*8;
    #pragma unroll
    for (int kk=0; kk<4; kk++){
      short8 a0 = *(const short8*)(aptr + kk*32);
      short8 a1 = *(const short8*)(aptr + 16*KP_ + kk*32);
      short8 b0 = *(const short8*)(bptr + kk*32);
      short8 b1 = *(const short8*)(bptr + 16*KP_ + kk*32);
      acc[0][0] = __builtin_amdgcn_mfma_f32_16x16x32_bf16(a0,b0,acc[0][0],0,0,0);
      acc[1][0] = __builtin_amdgcn_mfma_f32_16x16x32_bf16(a1,b0,acc[1][0],0,0,0);
      acc[0][1] = __builtin_amdgcn_mfma_f32_16x16x32_bf16(a0,b1,acc[0][1],0,0,0);
      acc[1][1] = __builtin_amdgcn_mfma_f32_16x16x32_bf16(a1,b1,acc[1][1],0,0,0);
    }
    if (half == 0){
      __syncthreads();     // done reading W half1
      for (int i = tid; i < 2048; i += 256){
        int n = i >> 4, k8 = (i & 15) << 3;
        *(short8*)&sW[n*KP_ + k8] = *(const short8*)(Wt2 + (size_t)n*128 + k8);
      }
      __syncthreads();
    }
  }
  __syncthreads();         // all mfma reads of sA done
  #pragma unroll
  for (int mt=0; mt<2; mt++){
    #pragma unroll
    for (int nt=0; nt<2; nt++){
      int col = n0 + nt*16 + lane15;
      float bsv = sbias[col];
      #pragma unroll
      for (int r4=0; r4<4; r4++){
        int row = mt*16 + quad*4 + r4;
        float v = acc[mt][nt][r4] + bsv + bf2f(skiph[(size_t)(base+row)*128 + col]);
        sA[row*KP_ + col] = f2bf(v);
      }
    }
  }
  __syncthreads();
  for (int i = tid; i < 512; i += 256){
    int row = i >> 4, seg = i & 15;
    *(short8*)(OUTH + (size_t)(base+row)*128 + seg*8) = *(const short8*)&sA[row*KP_ + seg*8];
  }
}

// ---------------- MFMA attention: one block per (b,l,head), 4 waves ---------
__global__ __launch_bounds__(256) void k_attn2(const unsigned short* __restrict__ QPh,
    const unsigned short* __restrict__ KPh, const unsigned short* __restrict__ VPh,
    unsigned short* __restrict__ AOh, int nrep, int nQ){
  __shared__ unsigned short Ksh[288*40];   // [key][32d + pad]
  __shared__ unsigned short Vt[32*296];    // [d][288key + pad]
  __shared__ unsigned short Psh[4*16*40];  // per-wave P tile
  __shared__ float rs[4*16];
  int hd = blockIdx.x & 3; int bl = blockIdx.x >> 2;
  size_t kvbase = (size_t)bl*264;
  int tid = threadIdx.x;
  for (int idx = tid; idx < 1056; idx += 256){     // K rows, vectorized
    int row = idx >> 2, seg = idx & 3;
    *(short8*)&Ksh[row*40 + seg*8] =
      *(const short8*)(KPh + (kvbase+row)*128 + hd*32 + seg*8);
  }
  for (int idx = tid; idx < 96; idx += 256){       // zero K pad rows
    int row = 264 + (idx>>2), seg = idx & 3;
    short8 z = {0,0,0,0,0,0,0,0};
    *(short8*)&Ksh[row*40 + seg*8] = z;
  }
  for (int idx = tid; idx < 1056; idx += 256){     // V transpose, vector reads
    int row = idx >> 2, seg = idx & 3;
    union { short8 s; unsigned short u[8]; } t;
    t.s = *(const short8*)(VPh + (kvbase+row)*128 + hd*32 + seg*8);
    #pragma unroll
    for (int i=0;i<8;i++) Vt[(seg*8+i)*296 + row] = t.u[i];
  }
  for (int idx = tid; idx < 384; idx += 256){      // zero V pad keys
    int d = idx / 12, kp = 264 + (idx % 12)*2;
    *(unsigned*)&Vt[d*296 + kp] = 0u;
  }
  __syncthreads();
  const int wv = tid >> 6, lane = tid & 63;
  const int lane15 = lane & 15, quad = lane >> 4;
  unsigned short* Pw = Psh + wv*640;
  float* rsw = rs + wv*16;
  short8 vfrag[9][2];
  #pragma unroll
  for (int kc=0; kc<9; kc++){
    vfrag[kc][0] = *(const short8*)&Vt[(lane15)*296      + kc*32 + quad*8];
    vfrag[kc][1] = *(const short8*)&Vt[(16+lane15)*296   + kc*32 + quad*8];
  }
  f32x4 macc0 = (f32x4)0.f, macc1 = (f32x4)0.f;
  for (int cam = 0; cam < nrep; cam++){
    int qrow = bl*nQ + (cam*4 + wv)*16 + lane15;
    short8 qf = *(const short8*)(QPh + (size_t)qrow*128 + hd*32 + quad*8);
    f32x4 oa0 = (f32x4)0.f, oa1 = (f32x4)0.f;
    float rsum = 0.f;
    #pragma unroll
    for (int kc=0; kc<9; kc++){
      #pragma unroll
      for (int sub=0; sub<2; sub++){
        int kt = kc*2 + sub;
        short8 kf = *(const short8*)&Ksh[(kt*16 + lane15)*40 + quad*8];
        f32x4 st = __builtin_amdgcn_mfma_f32_16x16x32_bf16(kf, qf, (f32x4)0.f, 0,0,0);
        int kbase = kt*16 + quad*4;
        float e0 = (kbase+0 < 264) ? __expf(st[0]) : 0.f;
        float e1 = (kbase+1 < 264) ? __expf(st[1]) : 0.f;
        float e2 = (kbase+2 < 264) ? __expf(st[2]) : 0.f;
        float e3 = (kbase+3 < 264) ? __expf(st[3]) : 0.f;
        rsum += (e0+e1)+(e2+e3);
        uint2 pk;
        pk.x = (unsigned)f2bf(e0) | ((unsigned)f2bf(e1) << 16);
        pk.y = (unsigned)f2bf(e2) | ((unsigned)f2bf(e3) << 16);
        *(uint2*)&Pw[lane15*40 + sub*16 + quad*4] = pk;
      }
      short8 pf = *(const short8*)&Pw[lane15*40 + quad*8];
      oa0 = __builtin_amdgcn_mfma_f32_16x16x32_bf16(pf, vfrag[kc][0], oa0, 0,0,0);
      oa1 = __builtin_amdgcn_mfma_f32_16x16x32_bf16(pf, vfrag[kc][1], oa1, 0,0,0);
    }
    rsum += __shfl_xor(rsum, 16);
    rsum += __shfl_xor(rsum, 32);
    if (lane < 16) rsw[lane] = rsum;
    f32x4 rv = *(f32x4*)&rsw[quad*4];
    #pragma unroll
    for (int r=0;r<4;r++){
      float inv = 1.f / rv[r];
      macc0[r] = fmaf(oa0[r], inv, macc0[r]);
      macc1[r] = fmaf(oa1[r], inv, macc1[r]);
    }
  }
  float sc = (nrep == 6) ? (1.f/6.f) : 1.f;
  int pixb = wv*16 + quad*4;
  #pragma unroll
  for (int r=0;r<4;r++){
    size_t rowo = ((size_t)(bl*64 + pixb + r))*128 + hd*32;
    AOh[rowo + lane15]      = f2bf(macc0[r]*sc);
    AOh[rowo + 16 + lane15] = f2bf(macc1[r]*sc);
  }
}

// ---------------- final LN (bf16 in) + transpose to (B,128,64,64) fp32 ------
__global__ __launch_bounds__(128) void k_final(const unsigned short* __restrict__ Xh,
    const float* __restrict__ g, const float* __restrict__ be,
    float* __restrict__ out){
  __shared__ float st[1024];
  __shared__ float sm[8], sr[8];
  int r0 = blockIdx.x*8;
  int b = r0 >> 12, l = (r0 >> 6) & 63, p0 = r0 & 63;
  int h = (l >> 3)*8 + (p0 >> 3);
  int wbase = (l & 7)*8;
  {
    union { short8 s; unsigned short u[8]; } t;
    t.s = *(const short8*)(Xh + (size_t)r0*128 + threadIdx.x*8);
    #pragma unroll
    for (int i=0;i<8;i++) st[threadIdx.x*8 + i] = bf2f(t.u[i]);
  }
  __syncthreads();
  int xid = threadIdx.x >> 4, part = threadIdx.x & 15;
  float s=0.f, s2=0.f;
  #pragma unroll
  for (int k=0;k<8;k++){
    float v = st[xid*128 + part*8 + k];
    s += v; s2 = fmaf(v,v,s2);
  }
  #pragma unroll
  for (int off=8; off>0; off>>=1){ s += __shfl_xor(s, off, 16); s2 += __shfl_xor(s2, off, 16); }
  if (part == 0){
    float mean = s*(1.f/128.f);
    sm[xid] = mean;
    sr[xid] = rsqrtf(fmaxf(s2*(1.f/128.f) - mean*mean, 0.f) + 1e-5f);
  }
  __syncthreads();
  int o = threadIdx.x;
  float go = g[o], bo = be[o];
  size_t obase = ((size_t)(b*128 + o))*4096 + h*64 + wbase;
  float res[8];
  #pragma unroll
  for (int x=0;x<8;x++) res[x] = fmaf((st[x*128+o]-sm[x])*sr[x], go, bo);
  *(float4*)&out[obase]   = make_float4(res[0],res[1],res[2],res[3]);
  *(float4*)&out[obase+4] = make_float4(res[4],res[5],res[6],res[7]);
}

extern "C" void kernel_launch(void* const* d_in, const int* in_sizes, int n_in,
                              void* d_out, int out_size, void* d_ws, size_t ws_size,
                              hipStream_t stream) {
  (void)in_sizes; (void)n_in; (void)out_size; (void)ws_size;
  const float* x     = (const float*)d_in[1];
  const float* gridp = (const float*)d_in[2];
  const float* feat  = (const float*)d_in[3];
  const float* Iinv  = (const float*)d_in[4];
  const float* Einv  = (const float*)d_in[5];
  const float* gfl   = (const float*)d_in[6];
  const float* bfl   = (const float*)d_in[7];
  const float* Wfl   = (const float*)d_in[8];
  const float* gfp   = (const float*)d_in[9];
  const float* bfp   = (const float*)d_in[10];
  const float* Wfp   = (const float*)d_in[11];
  const float* Wbev  = (const float*)d_in[12];
  const float* bbev  = (const float*)d_in[13];
  const float* Wimg  = (const float*)d_in[14];
  const float* Wcam  = (const float*)d_in[15];
  const float* alng  = (const float*)d_in[16];
  const float* alnb  = (const float*)d_in[17];
  const float* aWqkv = (const float*)d_in[18];
  const float* abqkv = (const float*)d_in[19];
  const float* aWp   = (const float*)d_in[20];
  const float* abp   = (const float*)d_in[21];
  const float* png   = (const float*)d_in[22];
  const float* pnb   = (const float*)d_in[23];
  const float* Wma   = (const float*)d_in[24];
  const float* bma   = (const float*)d_in[25];
  const float* Wmb   = (const float*)d_in[26];
  const float* bmb   = (const float*)d_in[27];
  const float* postg = (const float*)d_in[28];
  const float* postb = (const float*)d_in[29];
  float* out = (float*)d_out;
  float* ws  = (float*)d_ws;
  const float QSC = 0.17677669529663687f;   // 32^-0.5 folded into q projections

  unsigned short* Wt  = (unsigned short*)(ws + 2048);    // 294912 ush
  unsigned short* K1h = (unsigned short*)(ws + 149504);  // 33792x128
  unsigned short* V1h = K1h + 4325376;
  unsigned short* KPh = V1h + 4325376;                   // 128win x 264 x 128
  unsigned short* VPh = KPh + 4325376;
  unsigned short* QPh = VPh + 4325376;                   // 49152x128
  unsigned short* Qbh = QPh + 6291456;                   // 49152x128
  unsigned short* AOh = Qbh + 6291456;                   // 8192x128
  unsigned short* CURh= AOh + 1048576;
  unsigned short* Hh  = CURh + 1048576;                  // 8192x256
  unsigned short* Q1h = Hh + 2097152;
  unsigned short* Q2h = Q1h + 1048576;

  unsigned short* WtQ1 = Wt;            unsigned short* WtK1 = Wt + 16384;
  unsigned short* WtV1 = Wt + 32768;    unsigned short* WtQ2 = Wt + 49152;
  unsigned short* WtK2 = Wt + 65536;    unsigned short* WtV2 = Wt + 81920;
  unsigned short* WtP1 = Wt + 98304;    unsigned short* WtP2 = Wt + 114688;
  unsigned short* WtMA1 = Wt + 131072;  unsigned short* WtMA2 = Wt + 163840;
  unsigned short* WtMB1a = Wt + 196608; unsigned short* WtMB1b = Wt + 212992;
  unsigned short* WtMB2a = Wt + 229376; unsigned short* WtMB2b = Wt + 245760;
  unsigned short* WtFL = Wt + 262144;   unsigned short* WtFP = Wt + 278528;

  GArg Z{}; Z.oscale = 1.f;

  // 1) fused prep
  k_prep<<<10432, 128, 0, stream>>>(aWqkv, aWp, Wma, Wmb, Wfl, Wfp, Wt,
      Iinv, Einv, Wimg, Wcam, K1h, gridp, Wbev, bbev, x, alng, alnb, Qbh);

  // 2) conv K+V merged
  k_conv2<<<1056, 256, 0, stream>>>(feat, gfp, bfp, WtFP, K1h, K1h,
                                    gfl, bfl, WtFL, V1h);

  // 3) stage-1 Q+K+V projections merged (Q: M=49152; K,V: M=33792)
  {
    GArg q = Z, a = Z, b = Z;
    q.Xh=Qbh; q.ldx=128; q.Wt=WtQ1; q.bias=abqkv; q.OUTH=QPh; q.ldout=128;
    q.oscale=QSC;
    a.Xh=K1h; a.ldx=128; a.do_ln=1; a.lg=alng+128; a.lb=alnb+128;
    a.Wt=WtK1; a.bias=abqkv+128; a.OUTH=KPh; a.ldout=128; a.outmode=1;
    b = a; b.Xh=V1h; b.lg=alng+256; b.lb=alnb+256; b.Wt=WtV1;
    b.bias=abqkv+256; b.OUTH=VPh;
    k_gemm3<64><<<1824, 256, 0, stream>>>(q, a, b, 768, 1296);
  }
  // 4) stage-1 attention
  k_attn2<<<512, 256, 0, stream>>>(QPh, KPh, VPh, AOh, 6, 384);
  // 5) stage-1 out-projection + x skip
  {
    GArg a = Z;
    a.Xh=AOh; a.ldx=128; a.Wt=WtP1; a.bias=abp; a.OUTH=CURh; a.ldout=128;
    a.skip_mode=1; a.skipf=x;
    k_gemm3<32><<<256, 256, 0, stream>>>(a, a, a, 256, 256);
  }
  // 6) stage-1 MLP up (both halves merged)
  {
    GArg a = Z, b = Z;
    a.Xh=CURh; a.ldx=128; a.do_ln=1; a.lg=png; a.lb=pnb;
    a.Wt=WtMA1; a.bias=bma; a.OUTH=Hh; a.ldout=256; a.act=1;
    b = a; b.Wt=WtMA1+16384; b.bias=bma+128; b.OUTH=Hh+128;
    k_gemm3<32><<<512, 256, 0, stream>>>(a, b, b, 256, 512);
  }
  // 7) stage-1 MLP down (KT=256) + CUR skip
  k_gemm256<<<256, 256, 0, stream>>>(Hh, WtMB1a, WtMB1b, bmb, Q1h, CURh);

  // 8) stage-2 Q+K+V projections merged (Q2: M=8192; K,V: M=33792)
  {
    GArg q = Z, a = Z, b = Z;
    q.Xh=Q1h; q.ldx=128; q.do_ln=1; q.lg=alng+384; q.lb=alnb+384;
    q.Wt=WtQ2; q.bias=abqkv+384; q.OUTH=QPh; q.ldout=128; q.oscale=QSC;
    a.Xh=K1h; a.ldx=128; a.do_ln=1; a.lg=alng+512; a.lb=alnb+512;
    a.Wt=WtK2; a.bias=abqkv+512; a.OUTH=KPh; a.ldout=128; a.outmode=2;
    b = a; b.Xh=V1h; b.lg=alng+640; b.lb=alnb+640; b.Wt=WtV2;
    b.bias=abqkv+640; b.OUTH=VPh;
    k_gemm3<64><<<1184, 256, 0, stream>>>(q, a, b, 128, 656);
  }
  // 9) stage-2 attention
  k_attn2<<<512, 256, 0, stream>>>(QPh, KPh, VPh, AOh, 1, 64);
  // 10) stage-2 out-projection + Q1 skip
  {
    GArg a = Z;
    a.Xh=AOh; a.ldx=128; a.Wt=WtP2; a.bias=abp+128; a.OUTH=CURh; a.ldout=128;
    a.skip_mode=2; a.skiph=Q1h; a.ldskip=128;
    k_gemm3<32><<<256, 256, 0, stream>>>(a, a, a, 256, 256);
  }
  // 11) stage-2 MLP up
  {
    GArg a = Z, b = Z;
    a.Xh=CURh; a.ldx=128; a.do_ln=1; a.lg=png+128; a.lb=pnb+128;
    a.Wt=WtMA2; a.bias=bma+256; a.OUTH=Hh; a.ldout=256; a.act=1;
    b = a; b.Wt=WtMA2+16384; b.bias=bma+384; b.OUTH=Hh+128;
    k_gemm3<32><<<512, 256, 0, stream>>>(a, b, b, 256, 512);
  }
  // 12) stage-2 MLP down + CUR skip
  k_gemm256<<<256, 256, 0, stream>>>(Hh, WtMB2a, WtMB2b, bmb+128, Q2h, CURh);

  // 13) final LN + transpose
  k_final<<<1024, 128, 0, stream>>>(Q2h, postg, postb, out);
}